// Round 12
// baseline (125.211 us; speedup 1.0000x reference)
//
#include <hip/hip_runtime.h>
#include <hip/hip_fp16.h>

#define N_AG 512
#define TRAJ 16
#define TAU_ 2048
#define MSG_ 32768
#define HID_ 512
#define DV_ 64
#define SPLITQ 64
#define LDS_K 40            // qkgemm legacy layout

typedef _Float16 f16x8 __attribute__((ext_vector_type(8)));
typedef _Float16 f16x4 __attribute__((ext_vector_type(4)));
typedef _Float16 f16x2 __attribute__((ext_vector_type(2)));
typedef __fp16 h16x2 __attribute__((ext_vector_type(2)));
typedef float f32x4 __attribute__((ext_vector_type(4)));

#define VMCNT(n) asm volatile("s_waitcnt vmcnt(" #n ")" ::: "memory")
#define LGKM0    asm volatile("s_waitcnt lgkmcnt(0)" ::: "memory")
#define BAR()    __builtin_amdgcn_s_barrier()

__device__ __forceinline__ void gload16(const void* g, void* l) {
    __builtin_amdgcn_global_load_lds(
        (const __attribute__((address_space(1))) void*)g,
        (__attribute__((address_space(3))) void*)l, 16, 0, 0);
}

// ---------- prep_wq: Wqt[n][k] = (f16) Wq[k][n]  (R7-verified) ----------
__global__ __launch_bounds__(256) void prep_wq(const float* __restrict__ Wq,
                                               _Float16* __restrict__ Wqt)
{
    __shared__ float td[64][65];
    const int k0 = blockIdx.x * 64;   // 0..511
    const int n0 = blockIdx.y * 64;   // 0..7
    for (int e = threadIdx.x; e < 4096; e += 256) {
        const int ki = e >> 6, ni = e & 63;
        td[ki][ni] = Wq[(size_t)(k0 + ki) * HID_ + n0 + ni];
    }
    __syncthreads();
    for (int e = threadIdx.x; e < 4096; e += 256) {
        const int ni = e >> 6, ki = e & 63;
        Wqt[(size_t)(n0 + ni) * MSG_ + k0 + ki] = (_Float16)td[ki][ni];
    }
}

// ---------- prep_wv: Wvt[j][k] = (f16) Wv[k][j] ----------
__global__ __launch_bounds__(256) void prep_wv(const float* __restrict__ Wv,
                                               _Float16* __restrict__ Wvt)
{
    __shared__ float td[64][65];
    const int k0 = blockIdx.x * 64;
    for (int e = threadIdx.x; e < 4096; e += 256) {
        const int ki = e >> 6, ni = e & 63;
        td[ki][ni] = Wv[(size_t)(k0 + ki) * DV_ + ni];
    }
    __syncthreads();
    for (int e = threadIdx.x; e < 4096; e += 256) {
        const int ni = e >> 6, ki = e & 63;
        Wvt[(size_t)ni * TAU_ + k0 + ki] = (_Float16)td[ki][ni];
    }
}

// ---------- qgemm: qpart[s] = msgs[:, sK] @ Wq[sK, :]  (256x256 tile) ------
// 8 waves (2x4), SPLITQ=64, grid 256 (1 block/CU). A f32 reg-staged->f16
// (R11 proven layout, 0 conflicts); B fp16 via global_load_lds DMA from Wqt
// with pre-swizzled source (R7-proven). Depth-3 pipeline: 3 LDS buffer sets,
// VMCNT(12) steady state -- loads never drain inside the loop.
__global__ __launch_bounds__(512, 2) void qgemm(const float* __restrict__ X,
                                                const _Float16* __restrict__ Wqt,
                                                _Float16* __restrict__ qpart)
{
    // buf d (d=0,1,2): A @ d*32KB (16KB), B @ d*32KB+16KB (16KB)
    __shared__ __align__(1024) char smem[98304];
    const int tid = threadIdx.x;
    const int l = tid & 63;
    const int w = tid >> 6;
    const int wr = w >> 2, wc = w & 3;      // waves 2x4, wave tile 128x64
    const int r15 = l & 15;
    const int swz = ((l >> 4) ^ ((r15 >> 1) & 3)) * 16;

    const int b = blockIdx.x;
    const int sw = (b & 7) * 32 + (b >> 3);   // 256 = 8 XCD chunks of 32
    const int s = sw >> 2;                    // K-slice 0..63
    const int bm = (sw >> 1) & 1;
    const int bn = sw & 1;
    const size_t ks0 = (size_t)s * 512;

    // A staging: row am = tid>>1 (0..255), 16 floats at ak = (tid&1)*16
    const int am = tid >> 1;
    const int ak = (tid & 1) << 4;
    const float* agp = X + (size_t)(bm * 256 + am) * MSG_ + ks0 + ak;
    const int ac0 = ak >> 3;
    const int akey = (am >> 1) & 3;
    const int aoff0 = am * 64 + ((ac0 ^ akey)) * 16;
    const int aoff1 = am * 64 + (((ac0 + 1) ^ akey)) * 16;

    // B DMA: wave w instr j covers rows w*32+j*16..+15; source pre-swizzled
    const int bsrcc = (l & 3) ^ ((l >> 3) & 3);
    const _Float16* bgp = Wqt + (size_t)(bn * 256 + w * 32 + (l >> 2)) * MSG_
                          + ks0 + bsrcc * 8;
    const int bld0 = (w * 32) * 64;           // + j*1024 within B half

    f32x4 acc[8][4];
#pragma unroll
    for (int mi = 0; mi < 8; ++mi)
#pragma unroll
        for (int ni = 0; ni < 4; ++ni)
            acc[mi][ni] = (f32x4){0.f, 0.f, 0.f, 0.f};

    float4 r0[4], r1[4], r2[4];               // 3 named reg sets (static idx)

    auto aload = [&](float4 (&r)[4], int t) {
        const float* p = agp + t * 32;
#pragma unroll
        for (int i = 0; i < 4; ++i) r[i] = *(const float4*)(p + 4 * i);
    };
    auto awrite = [&](float4 (&r)[4], int d) {
        char* base = smem + d * 32768;
        const float* fa = (const float*)&r[0];
        union { h16x2 h2[4]; f16x8 v; } u0, u1;
        u0.h2[0] = __builtin_amdgcn_cvt_pkrtz(fa[0], fa[1]);
        u0.h2[1] = __builtin_amdgcn_cvt_pkrtz(fa[2], fa[3]);
        u0.h2[2] = __builtin_amdgcn_cvt_pkrtz(fa[4], fa[5]);
        u0.h2[3] = __builtin_amdgcn_cvt_pkrtz(fa[6], fa[7]);
        u1.h2[0] = __builtin_amdgcn_cvt_pkrtz(fa[8], fa[9]);
        u1.h2[1] = __builtin_amdgcn_cvt_pkrtz(fa[10], fa[11]);
        u1.h2[2] = __builtin_amdgcn_cvt_pkrtz(fa[12], fa[13]);
        u1.h2[3] = __builtin_amdgcn_cvt_pkrtz(fa[14], fa[15]);
        *(f16x8*)(base + aoff0) = u0.v;
        *(f16x8*)(base + aoff1) = u1.v;
    };
    auto bdma = [&](int t, int d) {
        char* base = smem + d * 32768 + 16384 + bld0;
        const _Float16* gp = bgp + (size_t)t * 32;
        gload16(gp, base);
        gload16(gp + (size_t)16 * MSG_, base + 1024);
    };
    auto compute = [&](int d) {
        const char* ab = smem + d * 32768;
        const char* bb = smem + d * 32768 + 16384;
        f16x8 af[8], bf[4];
#pragma unroll
        for (int mi = 0; mi < 8; ++mi)
            af[mi] = *(const f16x8*)(ab + (wr * 128 + mi * 16 + r15) * 64 + swz);
#pragma unroll
        for (int ni = 0; ni < 4; ++ni)
            bf[ni] = *(const f16x8*)(bb + (wc * 64 + ni * 16 + r15) * 64 + swz);
        __builtin_amdgcn_s_setprio(1);
#pragma unroll
        for (int mi = 0; mi < 8; ++mi)
#pragma unroll
            for (int ni = 0; ni < 4; ++ni)
                acc[mi][ni] = __builtin_amdgcn_mfma_f32_16x16x32_f16(
                    af[mi], bf[ni], acc[mi][ni], 0, 0, 0);
        __builtin_amdgcn_s_setprio(0);
    };

    // prologue: stages 0,1,2 in flight (6 VMEM ops each)
    bdma(0, 0); aload(r0, 0);
    bdma(1, 1); aload(r1, 1);
    bdma(2, 2); aload(r2, 2);
    VMCNT(12);            // stage 0 landed
    awrite(r0, 0);
    LGKM0; BAR();

    // iter t (buf t%3): compute t; issue t+3 into freed buf; wait t+1; stage A(t+1)
#define QSTEP(T, B0, RB, RW, B1)                       \
    compute(B0); BAR();                                \
    bdma((T) + 3, B0); aload(RB, (T) + 3);             \
    VMCNT(12);                                         \
    awrite(RW, B1);                                    \
    LGKM0; BAR();

    for (int g = 0; g < 4; ++g) {
        const int t = g * 3;
        QSTEP(t + 0, 0, r0, r1, 1)
        QSTEP(t + 1, 1, r1, r2, 2)
        QSTEP(t + 2, 2, r2, r0, 0)
    }
#undef QSTEP
    // t = 12: last issue (stage 15)
    compute(0); BAR();
    bdma(15, 0); aload(r0, 15);
    VMCNT(12);
    awrite(r1, 1);
    LGKM0; BAR();
    // t = 13
    compute(1); BAR();
    VMCNT(6);
    awrite(r2, 2);
    LGKM0; BAR();
    // t = 14
    compute(2); BAR();
    VMCNT(0);
    awrite(r0, 0);
    LGKM0; BAR();
    // t = 15
    compute(0);

    // epilogue: C/D layout col=lane&15, row=(lane>>4)*4+r
    _Float16* cp = qpart + (size_t)s * (N_AG * HID_);
#pragma unroll
    for (int mi = 0; mi < 8; ++mi)
#pragma unroll
        for (int ni = 0; ni < 4; ++ni) {
            const int row = bm * 256 + wr * 128 + mi * 16 + ((l >> 4) << 2);
            const int col = bn * 256 + wc * 64 + ni * 16 + r15;
#pragma unroll
            for (int r = 0; r < 4; ++r)
                cp[(size_t)(row + r) * HID_ + col] = (_Float16)acc[mi][ni][r];
        }
}

// ---------- qreduce: q = bq + sum_s qpart[s]  (f32) ----------
__global__ __launch_bounds__(256) void qreduce(const _Float16* __restrict__ qpart,
                                               const float* __restrict__ bq,
                                               float* __restrict__ q)
{
    const int e = blockIdx.x * 512 + threadIdx.x * 2;
    float a0 = bq[e & (HID_ - 1)], a1 = bq[(e + 1) & (HID_ - 1)];
#pragma unroll
    for (int s = 0; s < SPLITQ; ++s) {
        f16x2 p = *(const f16x2*)(qpart + (size_t)s * (N_AG * HID_) + e);
        a0 += (float)p[0];
        a1 += (float)p[1];
    }
    q[e] = a0;
    q[e + 1] = a1;
}

// ---------- qkgemm: qk[n][c] = sum_h q[n,h]*Wk[c,h]  (64x64 tile) ----------
__global__ __launch_bounds__(256, 4) void qkgemm(const float* __restrict__ q,
                                                 const float* __restrict__ Wk,
                                                 _Float16* __restrict__ qk)
{
    __shared__ __align__(16) _Float16 smem[4 * 64 * LDS_K];
    _Float16* As = smem;
    _Float16* Bs = smem + 2 * 64 * LDS_K;
    const int tid = threadIdx.x;
    const int lane = tid & 63;
    const int wid = tid >> 6;
    const int wr = wid >> 1;
    const int wc = wid & 1;
    const int r15 = lane & 15;
    const int kblk = (lane >> 4) << 3;

    const int b = blockIdx.x;
    const int w = (b & 7) * 32 + (b >> 3);
    const int bm = w >> 5;
    const int bn = w & 31;

    const bool isB = tid >= 128;
    const int rt = tid & 127;
    const int srow = rt >> 1;
    const int skh = (rt & 1) << 4;
    const float* gp = (isB ? Wk + (size_t)(bn * 64) * HID_ : q + (size_t)(bm * 64) * HID_)
                      + (size_t)srow * HID_ + skh;
    _Float16* lbase = (isB ? Bs : As) + srow * LDS_K + skh;

    f32x4 acc[2][2];
#pragma unroll
    for (int mi = 0; mi < 2; ++mi)
#pragma unroll
        for (int ni = 0; ni < 2; ++ni)
            acc[mi][ni] = (f32x4){0.f, 0.f, 0.f, 0.f};

    float4 rA[4], rB[4];
    auto load_stage = [&](float4 (&r)[4], int ks) {
#pragma unroll
        for (int i = 0; i < 4; ++i) r[i] = *(const float4*)(gp + ks + 4 * i);
    };
    auto write_stage = [&](float4 (&r)[4], int buf) {
        const float* f = (const float*)&r[0];
        f16x8 h0, h1;
#pragma unroll
        for (int i = 0; i < 8; ++i) { h0[i] = (_Float16)f[i]; h1[i] = (_Float16)f[8 + i]; }
        *(f16x8*)(lbase + buf * 64 * LDS_K) = h0;
        *(f16x8*)(lbase + buf * 64 * LDS_K + 8) = h1;
    };
    auto compute = [&](int buf) {
        const _Float16* ab = As + buf * 64 * LDS_K;
        const _Float16* bbp = Bs + buf * 64 * LDS_K;
        f16x8 af[2], bf[2];
#pragma unroll
        for (int mi = 0; mi < 2; ++mi)
            af[mi] = *(const f16x8*)(ab + (wr * 32 + mi * 16 + r15) * LDS_K + kblk);
#pragma unroll
        for (int ni = 0; ni < 2; ++ni)
            bf[ni] = *(const f16x8*)(bbp + (wc * 32 + ni * 16 + r15) * LDS_K + kblk);
#pragma unroll
        for (int mi = 0; mi < 2; ++mi)
#pragma unroll
            for (int ni = 0; ni < 2; ++ni)
                acc[mi][ni] = __builtin_amdgcn_mfma_f32_16x16x32_f16(
                    af[mi], bf[ni], acc[mi][ni], 0, 0, 0);
    };

    load_stage(rA, 0);
    load_stage(rB, 32);
    write_stage(rA, 0);
    __syncthreads();
    for (int t = 0; t < 16; t += 2) {
        if (t + 2 < 16) load_stage(rA, (t + 2) << 5);
        compute(0);
        if (t + 1 < 16) write_stage(rB, 1);
        __syncthreads();
        if (t + 3 < 16) load_stage(rB, (t + 3) << 5);
        compute(1);
        if (t + 2 < 16) write_stage(rA, 0);
        __syncthreads();
    }
#pragma unroll
    for (int mi = 0; mi < 2; ++mi)
#pragma unroll
        for (int ni = 0; ni < 2; ++ni) {
            const int row = bm * 64 + wr * 32 + mi * 16 + ((lane >> 4) << 2);
            const int col = bn * 64 + wc * 32 + ni * 16 + r15;
#pragma unroll
            for (int r = 0; r < 4; ++r)
                qk[(size_t)(row + r) * TAU_ + col] = (_Float16)acc[mi][ni][r];
        }
}

// ---------- svmix: scores -> softmax -> trajectory mix (taus cached in LDS) -
__global__ __launch_bounds__(256, 2) void svmix(const float* __restrict__ traj,
                                                const _Float16* __restrict__ qkm,
                                                _Float16* __restrict__ wmixg)
{
    const int n = blockIdx.x;
    const int tid = threadIdx.x;
    const int w = tid >> 6;
    const int l = tid & 63;
    __shared__ _Float16 tl[TRAJ][TAU_];   // 64 KB
    __shared__ float scrw[4][TRAJ];
    __shared__ float scr[TRAJ];

    const int c0 = tid * 8;
    f16x8 q8 = *(const f16x8*)(qkm + (size_t)n * TAU_ + c0);

#pragma unroll
    for (int t = 0; t < TRAJ; ++t) {
        const float* tr = traj + ((size_t)(t * N_AG + n)) * TAU_ + c0;
        float4 x0 = *(const float4*)(tr);
        float4 x1 = *(const float4*)(tr + 4);
        union { h16x2 h2[4]; f16x8 v; } u;
        u.h2[0] = __builtin_amdgcn_cvt_pkrtz(x0.x, x0.y);
        u.h2[1] = __builtin_amdgcn_cvt_pkrtz(x0.z, x0.w);
        u.h2[2] = __builtin_amdgcn_cvt_pkrtz(x1.x, x1.y);
        u.h2[3] = __builtin_amdgcn_cvt_pkrtz(x1.z, x1.w);
        *(f16x8*)(&tl[t][c0]) = u.v;
        float p = x0.x * (float)q8[0] + x0.y * (float)q8[1]
                + x0.z * (float)q8[2] + x0.w * (float)q8[3]
                + x1.x * (float)q8[4] + x1.y * (float)q8[5]
                + x1.z * (float)q8[6] + x1.w * (float)q8[7];
#pragma unroll
        for (int off = 32; off > 0; off >>= 1) p += __shfl_xor(p, off);
        if (l == 0) scrw[w][t] = p;
    }
    __syncthreads();
    if (tid < TRAJ)
        scr[tid] = scrw[0][tid] + scrw[1][tid] + scrw[2][tid] + scrw[3][tid];
    __syncthreads();

    const float inv = 0.04419417382415922f;  // 1/sqrt(512)
    float sv[TRAJ];
    float mx = -1e30f;
#pragma unroll
    for (int t = 0; t < TRAJ; ++t) { sv[t] = scr[t] * inv; mx = fmaxf(mx, sv[t]); }
    float ssum = 0.f;
#pragma unroll
    for (int t = 0; t < TRAJ; ++t) { sv[t] = expf(sv[t] - mx); ssum += sv[t]; }
    const float rs = 1.f / ssum;
#pragma unroll
    for (int t = 0; t < TRAJ; ++t) sv[t] *= rs;

    float o[8] = {0.f, 0.f, 0.f, 0.f, 0.f, 0.f, 0.f, 0.f};
#pragma unroll
    for (int t = 0; t < TRAJ; ++t) {
        f16x8 t8 = *(const f16x8*)(&tl[t][c0]);
#pragma unroll
        for (int i = 0; i < 8; ++i) o[i] += sv[t] * (float)t8[i];
    }
    f16x8 ho;
#pragma unroll
    for (int i = 0; i < 8; ++i) ho[i] = (_Float16)o[i];
    *(f16x8*)(wmixg + (size_t)n * TAU_ + c0) = ho;
}

// ---------- outgemm: out = wmixg @ Wv + bv  (batched, Wvt rows) ----------
__global__ __launch_bounds__(256) void outgemm(const _Float16* __restrict__ wmixg,
                                               const _Float16* __restrict__ Wvt,
                                               const float* __restrict__ bv,
                                               float* __restrict__ out)
{
    const int a0 = blockIdx.x * 8;   // grid 64
    const int tid = threadIdx.x;
    __shared__ _Float16 wl[8][TAU_];     // 32 KB
    __shared__ float pls[4][8][64];      // 8 KB

#pragma unroll
    for (int i = 0; i < 8; ++i) {
        const int slot = i * 256 + tid;
        const int row = slot >> 8;
        const int col = (slot & 255) * 8;
        *(f16x8*)(&wl[row][col]) = *(const f16x8*)(wmixg + (size_t)(a0 + row) * TAU_ + col);
    }
    __syncthreads();

    const int j = tid & 63;
    const int qh = tid >> 6;
    float pacc[8] = {0.f, 0.f, 0.f, 0.f, 0.f, 0.f, 0.f, 0.f};
    const _Float16* wv = Wvt + (size_t)j * TAU_ + qh * 512;
    for (int k = 0; k < 512; k += 8) {
        f16x8 w8 = *(const f16x8*)(wv + k);
        float wf[8];
#pragma unroll
        for (int i = 0; i < 8; ++i) wf[i] = (float)w8[i];
#pragma unroll
        for (int a = 0; a < 8; ++a) {
            f16x8 t8 = *(const f16x8*)(&wl[a][qh * 512 + k]);
#pragma unroll
            for (int i = 0; i < 8; ++i) pacc[a] += wf[i] * (float)t8[i];
        }
    }
#pragma unroll
    for (int a = 0; a < 8; ++a) pls[qh][a][j] = pacc[a];
    __syncthreads();

#pragma unroll
    for (int oo = 0; oo < 2; ++oo) {
        const int o = oo * 256 + tid;
        const int a = o >> 6, jj = o & 63;
        out[(size_t)(a0 + a) * DV_ + jj] =
            pls[0][a][jj] + pls[1][a][jj] + pls[2][a][jj] + pls[3][a][jj] + bv[jj];
    }
}

extern "C" void kernel_launch(void* const* d_in, const int* in_sizes, int n_in,
                              void* d_out, int out_size, void* d_ws, size_t ws_size,
                              hipStream_t stream)
{
    const float* traj = (const float*)d_in[0];  // [16,512,2048]
    const float* msgs = (const float*)d_in[1];  // [512, 32768]
    const float* Wq   = (const float*)d_in[2];  // [32768, 512]
    const float* bq   = (const float*)d_in[3];  // [512]
    const float* Wk   = (const float*)d_in[4];  // [2048, 512]
    const float* bk   = (const float*)d_in[5];  // [512] UNUSED (softmax-invariant)
    const float* Wv   = (const float*)d_in[6];  // [2048, 64]
    const float* bv   = (const float*)d_in[7];  // [64]
    float* out = (float*)d_out;                 // [512, 64]
    (void)bk;

    // ws: qpart f16 33.5MB | q f32 1MB | Wqt f16 33.5MB (dead after qgemm;
    // qk/Wvt/wmixg overlaid on it, all written post-qgemm). Total 68.2 MB.
    _Float16* qpart = (_Float16*)d_ws;
    float*    q     = (float*)(qpart + (size_t)SPLITQ * N_AG * HID_);
    _Float16* Wqt   = (_Float16*)(q + (size_t)N_AG * HID_);
    _Float16* qk    = Wqt;                               // alias (2 MB)
    _Float16* Wvt   = qk + (size_t)N_AG * TAU_;          // alias (+0.25 MB)
    _Float16* wmixg = Wvt + (size_t)DV_ * TAU_;          // alias (+2 MB)

    prep_wq<<<dim3(512, 8), 256, 0, stream>>>(Wq, Wqt);
    qgemm<<<256, 512, 0, stream>>>(msgs, Wqt, qpart);
    qreduce<<<512, 256, 0, stream>>>(qpart, bq, q);
    prep_wv<<<32, 256, 0, stream>>>(Wv, Wvt);
    qkgemm<<<256, 256, 0, stream>>>(q, Wk, qk);
    svmix<<<512, 256, 0, stream>>>(traj, qk, wmixg);
    outgemm<<<64, 256, 0, stream>>>(wmixg, Wvt, bv, out);
}

// Round 13
// 117.095 us; speedup vs baseline: 1.0693x; 1.0693x over previous
//
#include <hip/hip_runtime.h>
#include <hip/hip_fp16.h>

#define N_AG 512
#define TRAJ 16
#define TAU_ 2048
#define MSG_ 32768
#define HID_ 512
#define DV_ 64
#define SPLITQ 64
#define LDS_K 40            // qkgemm legacy layout

typedef _Float16 f16x8 __attribute__((ext_vector_type(8)));
typedef _Float16 f16x4 __attribute__((ext_vector_type(4)));
typedef _Float16 f16x2 __attribute__((ext_vector_type(2)));
typedef __fp16 h16x2 __attribute__((ext_vector_type(2)));
typedef float f32x4 __attribute__((ext_vector_type(4)));

#define VMCNT(n) asm volatile("s_waitcnt vmcnt(" #n ")" ::: "memory")
#define LGKM0    asm volatile("s_waitcnt lgkmcnt(0)" ::: "memory")
#define BAR()    __builtin_amdgcn_s_barrier()

__device__ __forceinline__ void gload16(const void* g, void* l) {
    __builtin_amdgcn_global_load_lds(
        (const __attribute__((address_space(1))) void*)g,
        (__attribute__((address_space(3))) void*)l, 16, 0, 0);
}

// ---------- prep_wq (vectorized): Wqt[n][k] = (f16) Wq[k][n] ----------
// 64k x 64n tile per block. Reads: 64 consecutive n per wave-row (256B).
// Writes: f16x8 per thread, 8 consecutive threads = 128B run.
__global__ __launch_bounds__(256) void prep_wq(const float* __restrict__ Wq,
                                               _Float16* __restrict__ Wqt)
{
    __shared__ float td[64][65];
    const int k0 = blockIdx.x * 64;   // 0..511
    const int n0 = blockIdx.y * 64;   // 0..7
    // load 64x64 f32 tile (each thread 16 scalar f32, coalesced 256B/wave)
#pragma unroll
    for (int p = 0; p < 16; ++p) {
        const int e = p * 256 + threadIdx.x;
        const int ki = e >> 6, ni = e & 63;
        td[ki][ni] = Wq[(size_t)(k0 + ki) * HID_ + n0 + ni];
    }
    __syncthreads();
    // write: unit u -> ni = u>>3, kj = u&7 (8 k's); f16x8 stores
#pragma unroll
    for (int p = 0; p < 2; ++p) {
        const int u = p * 256 + threadIdx.x;
        const int ni = u >> 3, kj = (u & 7) * 8;
        f16x8 h;
#pragma unroll
        for (int i = 0; i < 8; ++i) h[i] = (_Float16)td[kj + i][ni];
        *(f16x8*)(Wqt + (size_t)(n0 + ni) * MSG_ + k0 + kj) = h;
    }
}

// ---------- prep_wv: Wvt[j][k] = (f16) Wv[k][j] ----------
__global__ __launch_bounds__(256) void prep_wv(const float* __restrict__ Wv,
                                               _Float16* __restrict__ Wvt)
{
    __shared__ float td[64][65];
    const int k0 = blockIdx.x * 64;
    for (int e = threadIdx.x; e < 4096; e += 256) {
        const int ki = e >> 6, ni = e & 63;
        td[ki][ni] = Wv[(size_t)(k0 + ki) * DV_ + ni];
    }
    __syncthreads();
#pragma unroll
    for (int p = 0; p < 2; ++p) {
        const int u = p * 256 + threadIdx.x;
        const int ni = u >> 3, kj = (u & 7) * 8;
        f16x8 h;
#pragma unroll
        for (int i = 0; i < 8; ++i) h[i] = (_Float16)td[kj + i][ni];
        *(f16x8*)(Wvt + (size_t)ni * TAU_ + k0 + kj) = h;
    }
}

// ---------- qgemm: qpart[s] = msgs[:, sK] @ Wq[sK, :]  (256x256 tile) ------
// R12-proven: 8 waves (2x4), SPLITQ=64, grid 256. A f32 reg-staged->f16
// (0 conflicts); B fp16 global_load_lds DMA from Wqt, pre-swizzled source.
// Depth-3: 3 LDS buffer sets, VMCNT(12) steady, never drained in-loop.
__global__ __launch_bounds__(512, 2) void qgemm(const float* __restrict__ X,
                                                const _Float16* __restrict__ Wqt,
                                                _Float16* __restrict__ qpart)
{
    __shared__ __align__(1024) char smem[98304];
    const int tid = threadIdx.x;
    const int l = tid & 63;
    const int w = tid >> 6;
    const int wr = w >> 2, wc = w & 3;      // waves 2x4, wave tile 128x64
    const int r15 = l & 15;
    const int swz = ((l >> 4) ^ ((r15 >> 1) & 3)) * 16;

    const int b = blockIdx.x;
    const int sw = (b & 7) * 32 + (b >> 3);   // 256 = 8 XCD chunks of 32
    const int s = sw >> 2;                    // K-slice 0..63
    const int bm = (sw >> 1) & 1;
    const int bn = sw & 1;
    const size_t ks0 = (size_t)s * 512;

    const int am = tid >> 1;
    const int ak = (tid & 1) << 4;
    const float* agp = X + (size_t)(bm * 256 + am) * MSG_ + ks0 + ak;
    const int ac0 = ak >> 3;
    const int akey = (am >> 1) & 3;
    const int aoff0 = am * 64 + ((ac0 ^ akey)) * 16;
    const int aoff1 = am * 64 + (((ac0 + 1) ^ akey)) * 16;

    const int bsrcc = (l & 3) ^ ((l >> 3) & 3);
    const _Float16* bgp = Wqt + (size_t)(bn * 256 + w * 32 + (l >> 2)) * MSG_
                          + ks0 + bsrcc * 8;
    const int bld0 = (w * 32) * 64;

    f32x4 acc[8][4];
#pragma unroll
    for (int mi = 0; mi < 8; ++mi)
#pragma unroll
        for (int ni = 0; ni < 4; ++ni)
            acc[mi][ni] = (f32x4){0.f, 0.f, 0.f, 0.f};

    float4 r0[4], r1[4], r2[4];

    auto aload = [&](float4 (&r)[4], int t) {
        const float* p = agp + t * 32;
#pragma unroll
        for (int i = 0; i < 4; ++i) r[i] = *(const float4*)(p + 4 * i);
    };
    auto awrite = [&](float4 (&r)[4], int d) {
        char* base = smem + d * 32768;
        const float* fa = (const float*)&r[0];
        union { h16x2 h2[4]; f16x8 v; } u0, u1;
        u0.h2[0] = __builtin_amdgcn_cvt_pkrtz(fa[0], fa[1]);
        u0.h2[1] = __builtin_amdgcn_cvt_pkrtz(fa[2], fa[3]);
        u0.h2[2] = __builtin_amdgcn_cvt_pkrtz(fa[4], fa[5]);
        u0.h2[3] = __builtin_amdgcn_cvt_pkrtz(fa[6], fa[7]);
        u1.h2[0] = __builtin_amdgcn_cvt_pkrtz(fa[8], fa[9]);
        u1.h2[1] = __builtin_amdgcn_cvt_pkrtz(fa[10], fa[11]);
        u1.h2[2] = __builtin_amdgcn_cvt_pkrtz(fa[12], fa[13]);
        u1.h2[3] = __builtin_amdgcn_cvt_pkrtz(fa[14], fa[15]);
        *(f16x8*)(base + aoff0) = u0.v;
        *(f16x8*)(base + aoff1) = u1.v;
    };
    auto bdma = [&](int t, int d) {
        char* base = smem + d * 32768 + 16384 + bld0;
        const _Float16* gp = bgp + (size_t)t * 32;
        gload16(gp, base);
        gload16(gp + (size_t)16 * MSG_, base + 1024);
    };
    auto compute = [&](int d) {
        const char* ab = smem + d * 32768;
        const char* bb = smem + d * 32768 + 16384;
        f16x8 af[8], bf[4];
#pragma unroll
        for (int mi = 0; mi < 8; ++mi)
            af[mi] = *(const f16x8*)(ab + (wr * 128 + mi * 16 + r15) * 64 + swz);
#pragma unroll
        for (int ni = 0; ni < 4; ++ni)
            bf[ni] = *(const f16x8*)(bb + (wc * 64 + ni * 16 + r15) * 64 + swz);
        __builtin_amdgcn_s_setprio(1);
#pragma unroll
        for (int mi = 0; mi < 8; ++mi)
#pragma unroll
            for (int ni = 0; ni < 4; ++ni)
                acc[mi][ni] = __builtin_amdgcn_mfma_f32_16x16x32_f16(
                    af[mi], bf[ni], acc[mi][ni], 0, 0, 0);
        __builtin_amdgcn_s_setprio(0);
    };

    bdma(0, 0); aload(r0, 0);
    bdma(1, 1); aload(r1, 1);
    bdma(2, 2); aload(r2, 2);
    VMCNT(12);
    awrite(r0, 0);
    LGKM0; BAR();

#define QSTEP(T, B0, RB, RW, B1)                       \
    compute(B0); BAR();                                \
    bdma((T) + 3, B0); aload(RB, (T) + 3);             \
    VMCNT(12);                                         \
    awrite(RW, B1);                                    \
    LGKM0; BAR();

    for (int g = 0; g < 4; ++g) {
        const int t = g * 3;
        QSTEP(t + 0, 0, r0, r1, 1)
        QSTEP(t + 1, 1, r1, r2, 2)
        QSTEP(t + 2, 2, r2, r0, 0)
    }
#undef QSTEP
    compute(0); BAR();
    bdma(15, 0); aload(r0, 15);
    VMCNT(12);
    awrite(r1, 1);
    LGKM0; BAR();
    compute(1); BAR();
    VMCNT(6);
    awrite(r2, 2);
    LGKM0; BAR();
    compute(2); BAR();
    VMCNT(0);
    awrite(r0, 0);
    LGKM0; BAR();
    compute(0);

    _Float16* cp = qpart + (size_t)s * (N_AG * HID_);
#pragma unroll
    for (int mi = 0; mi < 8; ++mi)
#pragma unroll
        for (int ni = 0; ni < 4; ++ni) {
            const int row = bm * 256 + wr * 128 + mi * 16 + ((l >> 4) << 2);
            const int col = bn * 256 + wc * 64 + ni * 16 + r15;
#pragma unroll
            for (int r = 0; r < 4; ++r)
                cp[(size_t)(row + r) * HID_ + col] = (_Float16)acc[mi][ni][r];
        }
}

// ---------- qreduce (vectorized): q = bq + sum_s qpart[s]  (f32) ----------
__global__ __launch_bounds__(256) void qreduce(const _Float16* __restrict__ qpart,
                                               const float* __restrict__ bq,
                                               float* __restrict__ q)
{
    const int e = (blockIdx.x * 256 + threadIdx.x) * 8;   // grid 128
    const int h0 = e & (HID_ - 1);
    float a[8];
#pragma unroll
    for (int i = 0; i < 8; ++i) a[i] = bq[h0 + i];
#pragma unroll
    for (int s = 0; s < SPLITQ; ++s) {
        f16x8 p = *(const f16x8*)(qpart + (size_t)s * (N_AG * HID_) + e);
#pragma unroll
        for (int i = 0; i < 8; ++i) a[i] += (float)p[i];
    }
    *(float4*)(q + e)     = (float4){a[0], a[1], a[2], a[3]};
    *(float4*)(q + e + 4) = (float4){a[4], a[5], a[6], a[7]};
}

// ---------- qkgemm: qk[n][c] = sum_h q[n,h]*Wk[c,h]  (64x64 tile) ----------
__global__ __launch_bounds__(256, 4) void qkgemm(const float* __restrict__ q,
                                                 const float* __restrict__ Wk,
                                                 _Float16* __restrict__ qk)
{
    __shared__ __align__(16) _Float16 smem[4 * 64 * LDS_K];
    _Float16* As = smem;
    _Float16* Bs = smem + 2 * 64 * LDS_K;
    const int tid = threadIdx.x;
    const int lane = tid & 63;
    const int wid = tid >> 6;
    const int wr = wid >> 1;
    const int wc = wid & 1;
    const int r15 = lane & 15;
    const int kblk = (lane >> 4) << 3;

    const int b = blockIdx.x;
    const int w = (b & 7) * 32 + (b >> 3);
    const int bm = w >> 5;
    const int bn = w & 31;

    const bool isB = tid >= 128;
    const int rt = tid & 127;
    const int srow = rt >> 1;
    const int skh = (rt & 1) << 4;
    const float* gp = (isB ? Wk + (size_t)(bn * 64) * HID_ : q + (size_t)(bm * 64) * HID_)
                      + (size_t)srow * HID_ + skh;
    _Float16* lbase = (isB ? Bs : As) + srow * LDS_K + skh;

    f32x4 acc[2][2];
#pragma unroll
    for (int mi = 0; mi < 2; ++mi)
#pragma unroll
        for (int ni = 0; ni < 2; ++ni)
            acc[mi][ni] = (f32x4){0.f, 0.f, 0.f, 0.f};

    float4 rA[4], rB[4];
    auto load_stage = [&](float4 (&r)[4], int ks) {
#pragma unroll
        for (int i = 0; i < 4; ++i) r[i] = *(const float4*)(gp + ks + 4 * i);
    };
    auto write_stage = [&](float4 (&r)[4], int buf) {
        const float* f = (const float*)&r[0];
        f16x8 h0, h1;
#pragma unroll
        for (int i = 0; i < 8; ++i) { h0[i] = (_Float16)f[i]; h1[i] = (_Float16)f[8 + i]; }
        *(f16x8*)(lbase + buf * 64 * LDS_K) = h0;
        *(f16x8*)(lbase + buf * 64 * LDS_K + 8) = h1;
    };
    auto compute = [&](int buf) {
        const _Float16* ab = As + buf * 64 * LDS_K;
        const _Float16* bbp = Bs + buf * 64 * LDS_K;
        f16x8 af[2], bf[2];
#pragma unroll
        for (int mi = 0; mi < 2; ++mi)
            af[mi] = *(const f16x8*)(ab + (wr * 32 + mi * 16 + r15) * LDS_K + kblk);
#pragma unroll
        for (int ni = 0; ni < 2; ++ni)
            bf[ni] = *(const f16x8*)(bbp + (wc * 32 + ni * 16 + r15) * LDS_K + kblk);
#pragma unroll
        for (int mi = 0; mi < 2; ++mi)
#pragma unroll
            for (int ni = 0; ni < 2; ++ni)
                acc[mi][ni] = __builtin_amdgcn_mfma_f32_16x16x32_f16(
                    af[mi], bf[ni], acc[mi][ni], 0, 0, 0);
    };

    load_stage(rA, 0);
    load_stage(rB, 32);
    write_stage(rA, 0);
    __syncthreads();
    for (int t = 0; t < 16; t += 2) {
        if (t + 2 < 16) load_stage(rA, (t + 2) << 5);
        compute(0);
        if (t + 1 < 16) write_stage(rB, 1);
        __syncthreads();
        if (t + 3 < 16) load_stage(rB, (t + 3) << 5);
        compute(1);
        if (t + 2 < 16) write_stage(rA, 0);
        __syncthreads();
    }
#pragma unroll
    for (int mi = 0; mi < 2; ++mi)
#pragma unroll
        for (int ni = 0; ni < 2; ++ni) {
            const int row = bm * 64 + wr * 32 + mi * 16 + ((lane >> 4) << 2);
            const int col = bn * 64 + wc * 32 + ni * 16 + r15;
#pragma unroll
            for (int r = 0; r < 4; ++r)
                qk[(size_t)(row + r) * TAU_ + col] = (_Float16)acc[mi][ni][r];
        }
}

// ---------- svmix: scores -> softmax -> trajectory mix (taus cached in LDS) -
__global__ __launch_bounds__(256, 2) void svmix(const float* __restrict__ traj,
                                                const _Float16* __restrict__ qkm,
                                                _Float16* __restrict__ wmixg)
{
    const int n = blockIdx.x;
    const int tid = threadIdx.x;
    const int w = tid >> 6;
    const int l = tid & 63;
    __shared__ _Float16 tl[TRAJ][TAU_];   // 64 KB
    __shared__ float scrw[4][TRAJ];
    __shared__ float scr[TRAJ];

    const int c0 = tid * 8;
    f16x8 q8 = *(const f16x8*)(qkm + (size_t)n * TAU_ + c0);

#pragma unroll
    for (int t = 0; t < TRAJ; ++t) {
        const float* tr = traj + ((size_t)(t * N_AG + n)) * TAU_ + c0;
        float4 x0 = *(const float4*)(tr);
        float4 x1 = *(const float4*)(tr + 4);
        union { h16x2 h2[4]; f16x8 v; } u;
        u.h2[0] = __builtin_amdgcn_cvt_pkrtz(x0.x, x0.y);
        u.h2[1] = __builtin_amdgcn_cvt_pkrtz(x0.z, x0.w);
        u.h2[2] = __builtin_amdgcn_cvt_pkrtz(x1.x, x1.y);
        u.h2[3] = __builtin_amdgcn_cvt_pkrtz(x1.z, x1.w);
        *(f16x8*)(&tl[t][c0]) = u.v;
        float p = x0.x * (float)q8[0] + x0.y * (float)q8[1]
                + x0.z * (float)q8[2] + x0.w * (float)q8[3]
                + x1.x * (float)q8[4] + x1.y * (float)q8[5]
                + x1.z * (float)q8[6] + x1.w * (float)q8[7];
#pragma unroll
        for (int off = 32; off > 0; off >>= 1) p += __shfl_xor(p, off);
        if (l == 0) scrw[w][t] = p;
    }
    __syncthreads();
    if (tid < TRAJ)
        scr[tid] = scrw[0][tid] + scrw[1][tid] + scrw[2][tid] + scrw[3][tid];
    __syncthreads();

    const float inv = 0.04419417382415922f;  // 1/sqrt(512)
    float sv[TRAJ];
    float mx = -1e30f;
#pragma unroll
    for (int t = 0; t < TRAJ; ++t) { sv[t] = scr[t] * inv; mx = fmaxf(mx, sv[t]); }
    float ssum = 0.f;
#pragma unroll
    for (int t = 0; t < TRAJ; ++t) { sv[t] = expf(sv[t] - mx); ssum += sv[t]; }
    const float rs = 1.f / ssum;
#pragma unroll
    for (int t = 0; t < TRAJ; ++t) sv[t] *= rs;

    float o[8] = {0.f, 0.f, 0.f, 0.f, 0.f, 0.f, 0.f, 0.f};
#pragma unroll
    for (int t = 0; t < TRAJ; ++t) {
        f16x8 t8 = *(const f16x8*)(&tl[t][c0]);
#pragma unroll
        for (int i = 0; i < 8; ++i) o[i] += sv[t] * (float)t8[i];
    }
    f16x8 ho;
#pragma unroll
    for (int i = 0; i < 8; ++i) ho[i] = (_Float16)o[i];
    *(f16x8*)(wmixg + (size_t)n * TAU_ + c0) = ho;
}

// ---------- outgemm: out = wmixg @ Wv + bv  (batched, Wvt rows) ----------
__global__ __launch_bounds__(256) void outgemm(const _Float16* __restrict__ wmixg,
                                               const _Float16* __restrict__ Wvt,
                                               const float* __restrict__ bv,
                                               float* __restrict__ out)
{
    const int a0 = blockIdx.x * 8;   // grid 64
    const int tid = threadIdx.x;
    __shared__ _Float16 wl[8][TAU_];     // 32 KB
    __shared__ float pls[4][8][64];      // 8 KB

#pragma unroll
    for (int i = 0; i < 8; ++i) {
        const int slot = i * 256 + tid;
        const int row = slot >> 8;
        const int col = (slot & 255) * 8;
        *(f16x8*)(&wl[row][col]) = *(const f16x8*)(wmixg + (size_t)(a0 + row) * TAU_ + col);
    }
    __syncthreads();

    const int j = tid & 63;
    const int qh = tid >> 6;
    float pacc[8] = {0.f, 0.f, 0.f, 0.f, 0.f, 0.f, 0.f, 0.f};
    const _Float16* wv = Wvt + (size_t)j * TAU_ + qh * 512;
    for (int k = 0; k < 512; k += 8) {
        f16x8 w8 = *(const f16x8*)(wv + k);
        float wf[8];
#pragma unroll
        for (int i = 0; i < 8; ++i) wf[i] = (float)w8[i];
#pragma unroll
        for (int a = 0; a < 8; ++a) {
            f16x8 t8 = *(const f16x8*)(&wl[a][qh * 512 + k]);
#pragma unroll
            for (int i = 0; i < 8; ++i) pacc[a] += wf[i] * (float)t8[i];
        }
    }
#pragma unroll
    for (int a = 0; a < 8; ++a) pls[qh][a][j] = pacc[a];
    __syncthreads();

#pragma unroll
    for (int oo = 0; oo < 2; ++oo) {
        const int o = oo * 256 + tid;
        const int a = o >> 6, jj = o & 63;
        out[(size_t)(a0 + a) * DV_ + jj] =
            pls[0][a][jj] + pls[1][a][jj] + pls[2][a][jj] + pls[3][a][jj] + bv[jj];
    }
}

extern "C" void kernel_launch(void* const* d_in, const int* in_sizes, int n_in,
                              void* d_out, int out_size, void* d_ws, size_t ws_size,
                              hipStream_t stream)
{
    const float* traj = (const float*)d_in[0];  // [16,512,2048]
    const float* msgs = (const float*)d_in[1];  // [512, 32768]
    const float* Wq   = (const float*)d_in[2];  // [32768, 512]
    const float* bq   = (const float*)d_in[3];  // [512]
    const float* Wk   = (const float*)d_in[4];  // [2048, 512]
    const float* bk   = (const float*)d_in[5];  // [512] UNUSED (softmax-invariant)
    const float* Wv   = (const float*)d_in[6];  // [2048, 64]
    const float* bv   = (const float*)d_in[7];  // [64]
    float* out = (float*)d_out;                 // [512, 64]
    (void)bk;

    // ws: qpart f16 33.5MB | q f32 1MB | Wqt f16 33.5MB (dead after qgemm;
    // qk/Wvt/wmixg overlaid on it). Total 68.2 MB (R12-proven).
    _Float16* qpart = (_Float16*)d_ws;
    float*    q     = (float*)(qpart + (size_t)SPLITQ * N_AG * HID_);
    _Float16* Wqt   = (_Float16*)(q + (size_t)N_AG * HID_);
    _Float16* qk    = Wqt;                               // alias (2 MB)
    _Float16* Wvt   = qk + (size_t)N_AG * TAU_;          // alias (+0.25 MB)
    _Float16* wmixg = Wvt + (size_t)DV_ * TAU_;          // alias (+2 MB)

    prep_wq<<<dim3(512, 8), 256, 0, stream>>>(Wq, Wqt);
    qgemm<<<256, 512, 0, stream>>>(msgs, Wqt, qpart);
    qreduce<<<128, 256, 0, stream>>>(qpart, bq, q);
    prep_wv<<<32, 256, 0, stream>>>(Wv, Wvt);
    qkgemm<<<256, 256, 0, stream>>>(q, Wk, qk);
    svmix<<<512, 256, 0, stream>>>(traj, qk, wmixg);
    outgemm<<<64, 256, 0, stream>>>(wmixg, Wvt, bv, out);
}

// Round 14
// 112.164 us; speedup vs baseline: 1.1163x; 1.0440x over previous
//
#include <hip/hip_runtime.h>
#include <hip/hip_fp16.h>

#define N_AG 512
#define TRAJ 16
#define TAU_ 2048
#define MSG_ 32768
#define HID_ 512
#define DV_ 64
#define SPLITQ 128
#define LDS_K 40            // qkgemm legacy layout

typedef _Float16 f16x8 __attribute__((ext_vector_type(8)));
typedef _Float16 f16x4 __attribute__((ext_vector_type(4)));
typedef _Float16 f16x2 __attribute__((ext_vector_type(2)));
typedef __fp16 h16x2 __attribute__((ext_vector_type(2)));
typedef float f32x4 __attribute__((ext_vector_type(4)));

// ---------- prep_wv: Wvt[j][k] = (f16) Wv[k][j]  (vectorized writes) -------
__global__ __launch_bounds__(256) void prep_wv(const float* __restrict__ Wv,
                                               _Float16* __restrict__ Wvt)
{
    __shared__ float td[64][65];
    const int k0 = blockIdx.x * 64;
    for (int e = threadIdx.x; e < 4096; e += 256) {
        const int ki = e >> 6, ni = e & 63;
        td[ki][ni] = Wv[(size_t)(k0 + ki) * DV_ + ni];
    }
    __syncthreads();
#pragma unroll
    for (int p = 0; p < 2; ++p) {
        const int u = p * 256 + threadIdx.x;
        const int ni = u >> 3, kj = (u & 7) * 8;
        f16x8 h;
#pragma unroll
        for (int i = 0; i < 8; ++i) h[i] = (_Float16)td[kj + i][ni];
        *(f16x8*)(Wvt + (size_t)ni * TAU_ + k0 + kj) = h;
    }
}

// ---------- qgemm: qpart[s] = msgs[:, sK] @ Wq[sK, :]  (256x256 tile) ------
// R11 structure (f32 B staging, no prep), SPLITQ=128 -> grid 512 = 2
// blocks/CU for cross-block latency hiding. 64B-row k-major LDS with
// chunk-XOR swizzle (measured 0 conflicts). Depth-2 reg prefetch.
__global__ __launch_bounds__(512, 2) void qgemm(const float* __restrict__ X,
                                                const float* __restrict__ Wq,
                                                _Float16* __restrict__ qpart)
{
    // buf d: A @ d*32KB (16KB), B @ d*32KB+16KB (16KB)
    __shared__ __align__(1024) char smem[65536];
    const int tid = threadIdx.x;
    const int l = tid & 63;
    const int w = tid >> 6;
    const int wr = w >> 2, wc = w & 3;      // waves 2x4, wave tile 128x64
    const int r15 = l & 15;
    const int swz = ((l >> 4) ^ ((r15 >> 1) & 3)) * 16;

    const int b = blockIdx.x;
    const int sw = (b & 7) * 64 + (b >> 3);   // 512 = 8 XCD chunks of 64
    const int s = sw >> 2;                    // K-slice 0..127
    const int bm = (sw >> 1) & 1;
    const int bn = sw & 1;
    const size_t ks0 = (size_t)s * 256;

    // A staging: row am = tid>>1 (0..255), 16 floats at ak = (tid&1)*16
    const int am = tid >> 1;
    const int ak = (tid & 1) << 4;
    const float* agp = X + (size_t)(bm * 256 + am) * MSG_ + ks0 + ak;
    const int ac0 = ak >> 3;
    const int akey = (am >> 1) & 3;
    const int aoff0 = am * 64 + ((ac0 ^ akey)) * 16;
    const int aoff1 = am * 64 + (((ac0 + 1) ^ akey)) * 16;

    // B staging: col n = tid&255, 16 k's at kh0 = (tid>>8)*16 (k-strided)
    const int bn_ = tid & 255;
    const int kh0 = (tid >> 8) << 4;
    const float* bgp = Wq + (size_t)(ks0 + kh0) * HID_ + bn * 256 + bn_;
    const int bc0 = kh0 >> 3;
    const int bkey = (bn_ >> 1) & 3;
    const int boff0 = bn_ * 64 + ((bc0 ^ bkey)) * 16;
    const int boff1 = bn_ * 64 + (((bc0 + 1) ^ bkey)) * 16;

    f32x4 acc[8][4];
#pragma unroll
    for (int mi = 0; mi < 8; ++mi)
#pragma unroll
        for (int ni = 0; ni < 4; ++ni)
            acc[mi][ni] = (f32x4){0.f, 0.f, 0.f, 0.f};

    struct Stage { float4 a[4]; float bb[16]; };
    Stage rA, rB;
    const int nt = 8;                         // 256 / 32

    auto load_stage = [&](Stage& r, int t) {
        const float* ap = agp + t * 32;
#pragma unroll
        for (int i = 0; i < 4; ++i) r.a[i] = *(const float4*)(ap + 4 * i);
        const float* bp = bgp + (size_t)t * 32 * HID_;
#pragma unroll
        for (int i = 0; i < 16; ++i) r.bb[i] = bp[(size_t)i * HID_];
    };
    auto write_stage = [&](Stage& r, int d) {
        char* base = smem + d * 32768;
        const float* fa = (const float*)&r.a[0];
        union { h16x2 h2[4]; f16x8 v; } u0, u1;
        u0.h2[0] = __builtin_amdgcn_cvt_pkrtz(fa[0], fa[1]);
        u0.h2[1] = __builtin_amdgcn_cvt_pkrtz(fa[2], fa[3]);
        u0.h2[2] = __builtin_amdgcn_cvt_pkrtz(fa[4], fa[5]);
        u0.h2[3] = __builtin_amdgcn_cvt_pkrtz(fa[6], fa[7]);
        u1.h2[0] = __builtin_amdgcn_cvt_pkrtz(fa[8], fa[9]);
        u1.h2[1] = __builtin_amdgcn_cvt_pkrtz(fa[10], fa[11]);
        u1.h2[2] = __builtin_amdgcn_cvt_pkrtz(fa[12], fa[13]);
        u1.h2[3] = __builtin_amdgcn_cvt_pkrtz(fa[14], fa[15]);
        *(f16x8*)(base + aoff0) = u0.v;
        *(f16x8*)(base + aoff1) = u1.v;
        union { h16x2 h2[4]; f16x8 v; } v0, v1;
        v0.h2[0] = __builtin_amdgcn_cvt_pkrtz(r.bb[0], r.bb[1]);
        v0.h2[1] = __builtin_amdgcn_cvt_pkrtz(r.bb[2], r.bb[3]);
        v0.h2[2] = __builtin_amdgcn_cvt_pkrtz(r.bb[4], r.bb[5]);
        v0.h2[3] = __builtin_amdgcn_cvt_pkrtz(r.bb[6], r.bb[7]);
        v1.h2[0] = __builtin_amdgcn_cvt_pkrtz(r.bb[8], r.bb[9]);
        v1.h2[1] = __builtin_amdgcn_cvt_pkrtz(r.bb[10], r.bb[11]);
        v1.h2[2] = __builtin_amdgcn_cvt_pkrtz(r.bb[12], r.bb[13]);
        v1.h2[3] = __builtin_amdgcn_cvt_pkrtz(r.bb[14], r.bb[15]);
        *(f16x8*)(base + 16384 + boff0) = v0.v;
        *(f16x8*)(base + 16384 + boff1) = v1.v;
    };
    auto compute = [&](int d) {
        const char* ab = smem + d * 32768;
        const char* bb = smem + d * 32768 + 16384;
        f16x8 af[8], bf[4];
#pragma unroll
        for (int mi = 0; mi < 8; ++mi)
            af[mi] = *(const f16x8*)(ab + (wr * 128 + mi * 16 + r15) * 64 + swz);
#pragma unroll
        for (int ni = 0; ni < 4; ++ni)
            bf[ni] = *(const f16x8*)(bb + (wc * 64 + ni * 16 + r15) * 64 + swz);
#pragma unroll
        for (int mi = 0; mi < 8; ++mi)
#pragma unroll
            for (int ni = 0; ni < 4; ++ni)
                acc[mi][ni] = __builtin_amdgcn_mfma_f32_16x16x32_f16(
                    af[mi], bf[ni], acc[mi][ni], 0, 0, 0);
    };

    load_stage(rA, 0);
    load_stage(rB, 1);
    write_stage(rA, 0);
    __syncthreads();
    for (int t = 0; t < nt; t += 2) {
        if (t + 2 < nt) load_stage(rA, t + 2);
        compute(0);
        if (t + 1 < nt) write_stage(rB, 1);
        __syncthreads();
        if (t + 3 < nt) load_stage(rB, t + 3);
        compute(1);
        if (t + 2 < nt) write_stage(rA, 0);
        __syncthreads();
    }

    // C/D layout (HW-verified): col = lane&15, row = (lane>>4)*4 + reg
    _Float16* cp = qpart + (size_t)s * (N_AG * HID_);
#pragma unroll
    for (int mi = 0; mi < 8; ++mi)
#pragma unroll
        for (int ni = 0; ni < 4; ++ni) {
            const int row = bm * 256 + wr * 128 + mi * 16 + ((l >> 4) << 2);
            const int col = bn * 256 + wc * 64 + ni * 16 + r15;
#pragma unroll
            for (int r = 0; r < 4; ++r)
                cp[(size_t)(row + r) * HID_ + col] = (_Float16)acc[mi][ni][r];
        }
}

// ---------- qreduce (vectorized): q = bq + sum_s qpart[s]  (f32) ----------
__global__ __launch_bounds__(256) void qreduce(const _Float16* __restrict__ qpart,
                                               const float* __restrict__ bq,
                                               float* __restrict__ q)
{
    const int e = (blockIdx.x * 256 + threadIdx.x) * 8;   // grid 128
    const int h0 = e & (HID_ - 1);
    float a[8];
#pragma unroll
    for (int i = 0; i < 8; ++i) a[i] = bq[h0 + i];
#pragma unroll
    for (int s = 0; s < SPLITQ; ++s) {
        f16x8 p = *(const f16x8*)(qpart + (size_t)s * (N_AG * HID_) + e);
#pragma unroll
        for (int i = 0; i < 8; ++i) a[i] += (float)p[i];
    }
    *(float4*)(q + e)     = (float4){a[0], a[1], a[2], a[3]};
    *(float4*)(q + e + 4) = (float4){a[4], a[5], a[6], a[7]};
}

// ---------- qkgemm: qk[n][c] = sum_h q[n,h]*Wk[c,h]  (64x64 tile) ----------
__global__ __launch_bounds__(256, 4) void qkgemm(const float* __restrict__ q,
                                                 const float* __restrict__ Wk,
                                                 _Float16* __restrict__ qk)
{
    __shared__ __align__(16) _Float16 smem[4 * 64 * LDS_K];
    _Float16* As = smem;
    _Float16* Bs = smem + 2 * 64 * LDS_K;
    const int tid = threadIdx.x;
    const int lane = tid & 63;
    const int wid = tid >> 6;
    const int wr = wid >> 1;
    const int wc = wid & 1;
    const int r15 = lane & 15;
    const int kblk = (lane >> 4) << 3;

    const int b = blockIdx.x;
    const int w = (b & 7) * 32 + (b >> 3);
    const int bm = w >> 5;
    const int bn = w & 31;

    const bool isB = tid >= 128;
    const int rt = tid & 127;
    const int srow = rt >> 1;
    const int skh = (rt & 1) << 4;
    const float* gp = (isB ? Wk + (size_t)(bn * 64) * HID_ : q + (size_t)(bm * 64) * HID_)
                      + (size_t)srow * HID_ + skh;
    _Float16* lbase = (isB ? Bs : As) + srow * LDS_K + skh;

    f32x4 acc[2][2];
#pragma unroll
    for (int mi = 0; mi < 2; ++mi)
#pragma unroll
        for (int ni = 0; ni < 2; ++ni)
            acc[mi][ni] = (f32x4){0.f, 0.f, 0.f, 0.f};

    float4 rA[4], rB[4];
    auto load_stage = [&](float4 (&r)[4], int ks) {
#pragma unroll
        for (int i = 0; i < 4; ++i) r[i] = *(const float4*)(gp + ks + 4 * i);
    };
    auto write_stage = [&](float4 (&r)[4], int buf) {
        const float* f = (const float*)&r[0];
        f16x8 h0, h1;
#pragma unroll
        for (int i = 0; i < 8; ++i) { h0[i] = (_Float16)f[i]; h1[i] = (_Float16)f[8 + i]; }
        *(f16x8*)(lbase + buf * 64 * LDS_K) = h0;
        *(f16x8*)(lbase + buf * 64 * LDS_K + 8) = h1;
    };
    auto compute = [&](int buf) {
        const _Float16* ab = As + buf * 64 * LDS_K;
        const _Float16* bbp = Bs + buf * 64 * LDS_K;
        f16x8 af[2], bf[2];
#pragma unroll
        for (int mi = 0; mi < 2; ++mi)
            af[mi] = *(const f16x8*)(ab + (wr * 32 + mi * 16 + r15) * LDS_K + kblk);
#pragma unroll
        for (int ni = 0; ni < 2; ++ni)
            bf[ni] = *(const f16x8*)(bbp + (wc * 32 + ni * 16 + r15) * LDS_K + kblk);
#pragma unroll
        for (int mi = 0; mi < 2; ++mi)
#pragma unroll
            for (int ni = 0; ni < 2; ++ni)
                acc[mi][ni] = __builtin_amdgcn_mfma_f32_16x16x32_f16(
                    af[mi], bf[ni], acc[mi][ni], 0, 0, 0);
    };

    load_stage(rA, 0);
    load_stage(rB, 32);
    write_stage(rA, 0);
    __syncthreads();
    for (int t = 0; t < 16; t += 2) {
        if (t + 2 < 16) load_stage(rA, (t + 2) << 5);
        compute(0);
        if (t + 1 < 16) write_stage(rB, 1);
        __syncthreads();
        if (t + 3 < 16) load_stage(rB, (t + 3) << 5);
        compute(1);
        if (t + 2 < 16) write_stage(rA, 0);
        __syncthreads();
    }
#pragma unroll
    for (int mi = 0; mi < 2; ++mi)
#pragma unroll
        for (int ni = 0; ni < 2; ++ni) {
            const int row = bm * 64 + wr * 32 + mi * 16 + ((lane >> 4) << 2);
            const int col = bn * 64 + wc * 32 + ni * 16 + r15;
#pragma unroll
            for (int r = 0; r < 4; ++r)
                qk[(size_t)(row + r) * TAU_ + col] = (_Float16)acc[mi][ni][r];
        }
}

// ---------- svmix: scores -> softmax -> trajectory mix (taus cached in LDS) -
__global__ __launch_bounds__(256, 2) void svmix(const float* __restrict__ traj,
                                                const _Float16* __restrict__ qkm,
                                                _Float16* __restrict__ wmixg)
{
    const int n = blockIdx.x;
    const int tid = threadIdx.x;
    const int w = tid >> 6;
    const int l = tid & 63;
    __shared__ _Float16 tl[TRAJ][TAU_];   // 64 KB
    __shared__ float scrw[4][TRAJ];
    __shared__ float scr[TRAJ];

    const int c0 = tid * 8;
    f16x8 q8 = *(const f16x8*)(qkm + (size_t)n * TAU_ + c0);

#pragma unroll
    for (int t = 0; t < TRAJ; ++t) {
        const float* tr = traj + ((size_t)(t * N_AG + n)) * TAU_ + c0;
        float4 x0 = *(const float4*)(tr);
        float4 x1 = *(const float4*)(tr + 4);
        union { h16x2 h2[4]; f16x8 v; } u;
        u.h2[0] = __builtin_amdgcn_cvt_pkrtz(x0.x, x0.y);
        u.h2[1] = __builtin_amdgcn_cvt_pkrtz(x0.z, x0.w);
        u.h2[2] = __builtin_amdgcn_cvt_pkrtz(x1.x, x1.y);
        u.h2[3] = __builtin_amdgcn_cvt_pkrtz(x1.z, x1.w);
        *(f16x8*)(&tl[t][c0]) = u.v;
        float p = x0.x * (float)q8[0] + x0.y * (float)q8[1]
                + x0.z * (float)q8[2] + x0.w * (float)q8[3]
                + x1.x * (float)q8[4] + x1.y * (float)q8[5]
                + x1.z * (float)q8[6] + x1.w * (float)q8[7];
#pragma unroll
        for (int off = 32; off > 0; off >>= 1) p += __shfl_xor(p, off);
        if (l == 0) scrw[w][t] = p;
    }
    __syncthreads();
    if (tid < TRAJ)
        scr[tid] = scrw[0][tid] + scrw[1][tid] + scrw[2][tid] + scrw[3][tid];
    __syncthreads();

    const float inv = 0.04419417382415922f;  // 1/sqrt(512)
    float sv[TRAJ];
    float mx = -1e30f;
#pragma unroll
    for (int t = 0; t < TRAJ; ++t) { sv[t] = scr[t] * inv; mx = fmaxf(mx, sv[t]); }
    float ssum = 0.f;
#pragma unroll
    for (int t = 0; t < TRAJ; ++t) { sv[t] = expf(sv[t] - mx); ssum += sv[t]; }
    const float rs = 1.f / ssum;
#pragma unroll
    for (int t = 0; t < TRAJ; ++t) sv[t] *= rs;

    float o[8] = {0.f, 0.f, 0.f, 0.f, 0.f, 0.f, 0.f, 0.f};
#pragma unroll
    for (int t = 0; t < TRAJ; ++t) {
        f16x8 t8 = *(const f16x8*)(&tl[t][c0]);
#pragma unroll
        for (int i = 0; i < 8; ++i) o[i] += sv[t] * (float)t8[i];
    }
    f16x8 ho;
#pragma unroll
    for (int i = 0; i < 8; ++i) ho[i] = (_Float16)o[i];
    *(f16x8*)(wmixg + (size_t)n * TAU_ + c0) = ho;
}

// ---------- outgemm: out = wmixg @ Wv + bv  (batched, Wvt rows) ----------
__global__ __launch_bounds__(256) void outgemm(const _Float16* __restrict__ wmixg,
                                               const _Float16* __restrict__ Wvt,
                                               const float* __restrict__ bv,
                                               float* __restrict__ out)
{
    const int a0 = blockIdx.x * 8;   // grid 64
    const int tid = threadIdx.x;
    __shared__ _Float16 wl[8][TAU_];     // 32 KB
    __shared__ float pls[4][8][64];      // 8 KB

#pragma unroll
    for (int i = 0; i < 8; ++i) {
        const int slot = i * 256 + tid;
        const int row = slot >> 8;
        const int col = (slot & 255) * 8;
        *(f16x8*)(&wl[row][col]) = *(const f16x8*)(wmixg + (size_t)(a0 + row) * TAU_ + col);
    }
    __syncthreads();

    const int j = tid & 63;
    const int qh = tid >> 6;
    float pacc[8] = {0.f, 0.f, 0.f, 0.f, 0.f, 0.f, 0.f, 0.f};
    const _Float16* wv = Wvt + (size_t)j * TAU_ + qh * 512;
    for (int k = 0; k < 512; k += 8) {
        f16x8 w8 = *(const f16x8*)(wv + k);
        float wf[8];
#pragma unroll
        for (int i = 0; i < 8; ++i) wf[i] = (float)w8[i];
#pragma unroll
        for (int a = 0; a < 8; ++a) {
            f16x8 t8 = *(const f16x8*)(&wl[a][qh * 512 + k]);
#pragma unroll
            for (int i = 0; i < 8; ++i) pacc[a] += wf[i] * (float)t8[i];
        }
    }
#pragma unroll
    for (int a = 0; a < 8; ++a) pls[qh][a][j] = pacc[a];
    __syncthreads();

#pragma unroll
    for (int oo = 0; oo < 2; ++oo) {
        const int o = oo * 256 + tid;
        const int a = o >> 6, jj = o & 63;
        out[(size_t)(a0 + a) * DV_ + jj] =
            pls[0][a][jj] + pls[1][a][jj] + pls[2][a][jj] + pls[3][a][jj] + bv[jj];
    }
}

extern "C" void kernel_launch(void* const* d_in, const int* in_sizes, int n_in,
                              void* d_out, int out_size, void* d_ws, size_t ws_size,
                              hipStream_t stream)
{
    const float* traj = (const float*)d_in[0];  // [16,512,2048]
    const float* msgs = (const float*)d_in[1];  // [512, 32768]
    const float* Wq   = (const float*)d_in[2];  // [32768, 512]
    const float* bq   = (const float*)d_in[3];  // [512]
    const float* Wk   = (const float*)d_in[4];  // [2048, 512]
    const float* bk   = (const float*)d_in[5];  // [512] UNUSED (softmax-invariant)
    const float* Wv   = (const float*)d_in[6];  // [2048, 64]
    const float* bv   = (const float*)d_in[7];  // [64]
    float* out = (float*)d_out;                 // [512, 64]
    (void)bk;

    // ws: qpart f16 64MB | q f32 1MB. qk/Wvt/wmixg alias onto qpart (dead
    // after qreduce; all aliased writers run post-qreduce). Total 65 MB
    // (< R12-proven 68.2 MB).
    _Float16* qpart = (_Float16*)d_ws;
    float*    q     = (float*)(qpart + (size_t)SPLITQ * N_AG * HID_);
    _Float16* qk    = qpart;                             // alias (2 MB)
    _Float16* Wvt   = qk + (size_t)N_AG * TAU_;          // alias (+0.25 MB)
    _Float16* wmixg = Wvt + (size_t)DV_ * TAU_;          // alias (+2 MB)

    qgemm<<<512, 512, 0, stream>>>(msgs, Wq, qpart);
    qreduce<<<128, 256, 0, stream>>>(qpart, bq, q);
    prep_wv<<<32, 256, 0, stream>>>(Wv, Wvt);
    qkgemm<<<256, 256, 0, stream>>>(q, Wk, qk);
    svmix<<<512, 256, 0, stream>>>(traj, qk, wmixg);
    outgemm<<<64, 256, 0, stream>>>(wmixg, Wvt, bv, out);
}

// Round 15
// 108.165 us; speedup vs baseline: 1.1576x; 1.0370x over previous
//
#include <hip/hip_runtime.h>
#include <hip/hip_fp16.h>

#define N_AG 512
#define TRAJ 16
#define TAU_ 2048
#define MSG_ 32768
#define HID_ 512
#define DV_ 64
#define SPLITQ 64
#define LDS_K 40            // qkgemm legacy layout

typedef _Float16 f16x8 __attribute__((ext_vector_type(8)));
typedef _Float16 f16x4 __attribute__((ext_vector_type(4)));
typedef _Float16 f16x2 __attribute__((ext_vector_type(2)));
typedef __fp16 h16x2 __attribute__((ext_vector_type(2)));
typedef float f32x4 __attribute__((ext_vector_type(4)));

#define VMCNT(n) asm volatile("s_waitcnt vmcnt(" #n ")" ::: "memory")
#define LGKM0    asm volatile("s_waitcnt lgkmcnt(0)" ::: "memory")
#define BAR()    __builtin_amdgcn_s_barrier()

// ---------- prep_wv: Wvt[j][k] = (f16) Wv[k][j]  (vectorized writes) -------
__global__ __launch_bounds__(256) void prep_wv(const float* __restrict__ Wv,
                                               _Float16* __restrict__ Wvt)
{
    __shared__ float td[64][65];
    const int k0 = blockIdx.x * 64;
    for (int e = threadIdx.x; e < 4096; e += 256) {
        const int ki = e >> 6, ni = e & 63;
        td[ki][ni] = Wv[(size_t)(k0 + ki) * DV_ + ni];
    }
    __syncthreads();
#pragma unroll
    for (int p = 0; p < 2; ++p) {
        const int u = p * 256 + threadIdx.x;
        const int ni = u >> 3, kj = (u & 7) * 8;
        f16x8 h;
#pragma unroll
        for (int i = 0; i < 8; ++i) h[i] = (_Float16)td[kj + i][ni];
        *(f16x8*)(Wvt + (size_t)ni * TAU_ + k0 + kj) = h;
    }
}

// ---------- qgemm: qpart[s] = msgs[:, sK] @ Wq[sK, :]  (256x256 tile) ------
// R11 staging (f32 B, zero-conflict chunk-XOR LDS) + R12 schedule (depth-3
// ring, raw s_barrier, counted VMCNT(40) never drained in-loop). SPLITQ=64,
// grid 256 = 1 block/CU, 8 waves.
__global__ __launch_bounds__(512, 1) void qgemm(const float* __restrict__ X,
                                                const float* __restrict__ Wq,
                                                _Float16* __restrict__ qpart)
{
    // buf d (d=0,1,2): A @ d*32KB (16KB), B @ d*32KB+16KB (16KB)
    __shared__ __align__(1024) char smem[98304];
    const int tid = threadIdx.x;
    const int l = tid & 63;
    const int w = tid >> 6;
    const int wr = w >> 2, wc = w & 3;      // waves 2x4, wave tile 128x64
    const int r15 = l & 15;
    const int swz = ((l >> 4) ^ ((r15 >> 1) & 3)) * 16;

    const int b = blockIdx.x;
    const int sw = (b & 7) * 32 + (b >> 3);   // 256 = 8 XCD chunks of 32
    const int s = sw >> 2;                    // K-slice 0..63
    const int bm = (sw >> 1) & 1;
    const int bn = sw & 1;
    const size_t ks0 = (size_t)s * 512;

    // A staging: row am = tid>>1 (0..255), 16 floats at ak = (tid&1)*16
    const int am = tid >> 1;
    const int ak = (tid & 1) << 4;
    const float* agp = X + (size_t)(bm * 256 + am) * MSG_ + ks0 + ak;
    const int ac0 = ak >> 3;
    const int akey = (am >> 1) & 3;
    const int aoff0 = am * 64 + ((ac0 ^ akey)) * 16;
    const int aoff1 = am * 64 + (((ac0 + 1) ^ akey)) * 16;

    // B staging: col n = tid&255, 16 k's at kh0 = (tid>>8)*16 (k-strided)
    const int bn_ = tid & 255;
    const int kh0 = (tid >> 8) << 4;
    const float* bgp = Wq + (size_t)(ks0 + kh0) * HID_ + bn * 256 + bn_;
    const int bc0 = kh0 >> 3;
    const int bkey = (bn_ >> 1) & 3;
    const int boff0 = bn_ * 64 + ((bc0 ^ bkey)) * 16;
    const int boff1 = bn_ * 64 + (((bc0 + 1) ^ bkey)) * 16;

    f32x4 acc[8][4];
#pragma unroll
    for (int mi = 0; mi < 8; ++mi)
#pragma unroll
        for (int ni = 0; ni < 4; ++ni)
            acc[mi][ni] = (f32x4){0.f, 0.f, 0.f, 0.f};

    struct Stage { float4 a[4]; float bb[16]; };
    Stage r0, r1, r2;                         // depth-3 ring, static indices
    const int nt = 16;                        // 512 / 32

    auto load_stage = [&](Stage& r, int t) {
        const float* ap = agp + t * 32;
#pragma unroll
        for (int i = 0; i < 4; ++i) r.a[i] = *(const float4*)(ap + 4 * i);
        const float* bp = bgp + (size_t)t * 32 * HID_;
#pragma unroll
        for (int i = 0; i < 16; ++i) r.bb[i] = bp[(size_t)i * HID_];
    };
    auto write_stage = [&](Stage& r, int d) {
        char* base = smem + d * 32768;
        const float* fa = (const float*)&r.a[0];
        union { h16x2 h2[4]; f16x8 v; } u0, u1;
        u0.h2[0] = __builtin_amdgcn_cvt_pkrtz(fa[0], fa[1]);
        u0.h2[1] = __builtin_amdgcn_cvt_pkrtz(fa[2], fa[3]);
        u0.h2[2] = __builtin_amdgcn_cvt_pkrtz(fa[4], fa[5]);
        u0.h2[3] = __builtin_amdgcn_cvt_pkrtz(fa[6], fa[7]);
        u1.h2[0] = __builtin_amdgcn_cvt_pkrtz(fa[8], fa[9]);
        u1.h2[1] = __builtin_amdgcn_cvt_pkrtz(fa[10], fa[11]);
        u1.h2[2] = __builtin_amdgcn_cvt_pkrtz(fa[12], fa[13]);
        u1.h2[3] = __builtin_amdgcn_cvt_pkrtz(fa[14], fa[15]);
        *(f16x8*)(base + aoff0) = u0.v;
        *(f16x8*)(base + aoff1) = u1.v;
        union { h16x2 h2[4]; f16x8 v; } v0, v1;
        v0.h2[0] = __builtin_amdgcn_cvt_pkrtz(r.bb[0], r.bb[1]);
        v0.h2[1] = __builtin_amdgcn_cvt_pkrtz(r.bb[2], r.bb[3]);
        v0.h2[2] = __builtin_amdgcn_cvt_pkrtz(r.bb[4], r.bb[5]);
        v0.h2[3] = __builtin_amdgcn_cvt_pkrtz(r.bb[6], r.bb[7]);
        v1.h2[0] = __builtin_amdgcn_cvt_pkrtz(r.bb[8], r.bb[9]);
        v1.h2[1] = __builtin_amdgcn_cvt_pkrtz(r.bb[10], r.bb[11]);
        v1.h2[2] = __builtin_amdgcn_cvt_pkrtz(r.bb[12], r.bb[13]);
        v1.h2[3] = __builtin_amdgcn_cvt_pkrtz(r.bb[14], r.bb[15]);
        *(f16x8*)(base + 16384 + boff0) = v0.v;
        *(f16x8*)(base + 16384 + boff1) = v1.v;
    };
    auto compute = [&](int d) {
        const char* ab = smem + d * 32768;
        const char* bb = smem + d * 32768 + 16384;
        f16x8 af[8], bf[4];
#pragma unroll
        for (int mi = 0; mi < 8; ++mi)
            af[mi] = *(const f16x8*)(ab + (wr * 128 + mi * 16 + r15) * 64 + swz);
#pragma unroll
        for (int ni = 0; ni < 4; ++ni)
            bf[ni] = *(const f16x8*)(bb + (wc * 64 + ni * 16 + r15) * 64 + swz);
        __builtin_amdgcn_s_setprio(1);
#pragma unroll
        for (int mi = 0; mi < 8; ++mi)
#pragma unroll
            for (int ni = 0; ni < 4; ++ni)
                acc[mi][ni] = __builtin_amdgcn_mfma_f32_16x16x32_f16(
                    af[mi], bf[ni], acc[mi][ni], 0, 0, 0);
        __builtin_amdgcn_s_setprio(0);
    };

    // prologue: stages 0,1,2 in flight (20 VMEM instrs each)
    load_stage(r0, 0);
    load_stage(r1, 1);
    load_stage(r2, 2);
    VMCNT(40);            // stage 0 landed (leave 1,2 outstanding)
    write_stage(r0, 0);
    LGKM0; BAR();

    // iter t: compute buf t%3; issue stage t+3 into freed ring slot;
    // wait stage t+1 (VMCNT(40): 2 stages stay in flight); stage to LDS.
#define QSTEP(T, B0, RL, RW, B1)                       \
    compute(B0); BAR();                                \
    load_stage(RL, (T) + 3);                           \
    VMCNT(40);                                         \
    write_stage(RW, B1);                               \
    LGKM0; BAR();

    for (int g = 0; g < 4; ++g) {
        const int t = g * 3;
        QSTEP(t + 0, 0, r0, r1, 1)
        QSTEP(t + 1, 1, r1, r2, 2)
        QSTEP(t + 2, 2, r2, r0, 0)
    }
#undef QSTEP
    // t = 12: last issue (stage 15)
    compute(0); BAR();
    load_stage(r0, 15);
    VMCNT(40);
    write_stage(r1, 1);
    LGKM0; BAR();
    // t = 13
    compute(1); BAR();
    VMCNT(20);
    write_stage(r2, 2);
    LGKM0; BAR();
    // t = 14
    compute(2); BAR();
    VMCNT(0);
    write_stage(r0, 0);
    LGKM0; BAR();
    // t = 15
    compute(0);

    // C/D layout (HW-verified): col = lane&15, row = (lane>>4)*4 + reg
    _Float16* cp = qpart + (size_t)s * (N_AG * HID_);
#pragma unroll
    for (int mi = 0; mi < 8; ++mi)
#pragma unroll
        for (int ni = 0; ni < 4; ++ni) {
            const int row = bm * 256 + wr * 128 + mi * 16 + ((l >> 4) << 2);
            const int col = bn * 256 + wc * 64 + ni * 16 + r15;
#pragma unroll
            for (int r = 0; r < 4; ++r)
                cp[(size_t)(row + r) * HID_ + col] = (_Float16)acc[mi][ni][r];
        }
}

// ---------- qreduce (vectorized): q = bq + sum_s qpart[s]  (f32) ----------
__global__ __launch_bounds__(256) void qreduce(const _Float16* __restrict__ qpart,
                                               const float* __restrict__ bq,
                                               float* __restrict__ q)
{
    const int e = (blockIdx.x * 256 + threadIdx.x) * 8;   // grid 128
    const int h0 = e & (HID_ - 1);
    float a[8];
#pragma unroll
    for (int i = 0; i < 8; ++i) a[i] = bq[h0 + i];
#pragma unroll
    for (int s = 0; s < SPLITQ; ++s) {
        f16x8 p = *(const f16x8*)(qpart + (size_t)s * (N_AG * HID_) + e);
#pragma unroll
        for (int i = 0; i < 8; ++i) a[i] += (float)p[i];
    }
    *(float4*)(q + e)     = (float4){a[0], a[1], a[2], a[3]};
    *(float4*)(q + e + 4) = (float4){a[4], a[5], a[6], a[7]};
}

// ---------- qkgemm: qk[n][c] = sum_h q[n,h]*Wk[c,h]  (64x64 tile) ----------
__global__ __launch_bounds__(256, 4) void qkgemm(const float* __restrict__ q,
                                                 const float* __restrict__ Wk,
                                                 _Float16* __restrict__ qk)
{
    __shared__ __align__(16) _Float16 smem[4 * 64 * LDS_K];
    _Float16* As = smem;
    _Float16* Bs = smem + 2 * 64 * LDS_K;
    const int tid = threadIdx.x;
    const int lane = tid & 63;
    const int wid = tid >> 6;
    const int wr = wid >> 1;
    const int wc = wid & 1;
    const int r15 = lane & 15;
    const int kblk = (lane >> 4) << 3;

    const int b = blockIdx.x;
    const int w = (b & 7) * 32 + (b >> 3);
    const int bm = w >> 5;
    const int bn = w & 31;

    const bool isB = tid >= 128;
    const int rt = tid & 127;
    const int srow = rt >> 1;
    const int skh = (rt & 1) << 4;
    const float* gp = (isB ? Wk + (size_t)(bn * 64) * HID_ : q + (size_t)(bm * 64) * HID_)
                      + (size_t)srow * HID_ + skh;
    _Float16* lbase = (isB ? Bs : As) + srow * LDS_K + skh;

    f32x4 acc[2][2];
#pragma unroll
    for (int mi = 0; mi < 2; ++mi)
#pragma unroll
        for (int ni = 0; ni < 2; ++ni)
            acc[mi][ni] = (f32x4){0.f, 0.f, 0.f, 0.f};

    float4 rA[4], rB[4];
    auto load_stage = [&](float4 (&r)[4], int ks) {
#pragma unroll
        for (int i = 0; i < 4; ++i) r[i] = *(const float4*)(gp + ks + 4 * i);
    };
    auto write_stage = [&](float4 (&r)[4], int buf) {
        const float* f = (const float*)&r[0];
        f16x8 h0, h1;
#pragma unroll
        for (int i = 0; i < 8; ++i) { h0[i] = (_Float16)f[i]; h1[i] = (_Float16)f[8 + i]; }
        *(f16x8*)(lbase + buf * 64 * LDS_K) = h0;
        *(f16x8*)(lbase + buf * 64 * LDS_K + 8) = h1;
    };
    auto compute = [&](int buf) {
        const _Float16* ab = As + buf * 64 * LDS_K;
        const _Float16* bbp = Bs + buf * 64 * LDS_K;
        f16x8 af[2], bf[2];
#pragma unroll
        for (int mi = 0; mi < 2; ++mi)
            af[mi] = *(const f16x8*)(ab + (wr * 32 + mi * 16 + r15) * LDS_K + kblk);
#pragma unroll
        for (int ni = 0; ni < 2; ++ni)
            bf[ni] = *(const f16x8*)(bbp + (wc * 32 + ni * 16 + r15) * LDS_K + kblk);
#pragma unroll
        for (int mi = 0; mi < 2; ++mi)
#pragma unroll
            for (int ni = 0; ni < 2; ++ni)
                acc[mi][ni] = __builtin_amdgcn_mfma_f32_16x16x32_f16(
                    af[mi], bf[ni], acc[mi][ni], 0, 0, 0);
    };

    load_stage(rA, 0);
    load_stage(rB, 32);
    write_stage(rA, 0);
    __syncthreads();
    for (int t = 0; t < 16; t += 2) {
        if (t + 2 < 16) load_stage(rA, (t + 2) << 5);
        compute(0);
        if (t + 1 < 16) write_stage(rB, 1);
        __syncthreads();
        if (t + 3 < 16) load_stage(rB, (t + 3) << 5);
        compute(1);
        if (t + 2 < 16) write_stage(rA, 0);
        __syncthreads();
    }
#pragma unroll
    for (int mi = 0; mi < 2; ++mi)
#pragma unroll
        for (int ni = 0; ni < 2; ++ni) {
            const int row = bm * 64 + wr * 32 + mi * 16 + ((lane >> 4) << 2);
            const int col = bn * 64 + wc * 32 + ni * 16 + r15;
#pragma unroll
            for (int r = 0; r < 4; ++r)
                qk[(size_t)(row + r) * TAU_ + col] = (_Float16)acc[mi][ni][r];
        }
}

// ---------- svmix: scores -> softmax -> trajectory mix (taus cached in LDS) -
__global__ __launch_bounds__(256, 2) void svmix(const float* __restrict__ traj,
                                                const _Float16* __restrict__ qkm,
                                                _Float16* __restrict__ wmixg)
{
    const int n = blockIdx.x;
    const int tid = threadIdx.x;
    const int w = tid >> 6;
    const int l = tid & 63;
    __shared__ _Float16 tl[TRAJ][TAU_];   // 64 KB
    __shared__ float scrw[4][TRAJ];
    __shared__ float scr[TRAJ];

    const int c0 = tid * 8;
    f16x8 q8 = *(const f16x8*)(qkm + (size_t)n * TAU_ + c0);

#pragma unroll
    for (int t = 0; t < TRAJ; ++t) {
        const float* tr = traj + ((size_t)(t * N_AG + n)) * TAU_ + c0;
        float4 x0 = *(const float4*)(tr);
        float4 x1 = *(const float4*)(tr + 4);
        union { h16x2 h2[4]; f16x8 v; } u;
        u.h2[0] = __builtin_amdgcn_cvt_pkrtz(x0.x, x0.y);
        u.h2[1] = __builtin_amdgcn_cvt_pkrtz(x0.z, x0.w);
        u.h2[2] = __builtin_amdgcn_cvt_pkrtz(x1.x, x1.y);
        u.h2[3] = __builtin_amdgcn_cvt_pkrtz(x1.z, x1.w);
        *(f16x8*)(&tl[t][c0]) = u.v;
        float p = x0.x * (float)q8[0] + x0.y * (float)q8[1]
                + x0.z * (float)q8[2] + x0.w * (float)q8[3]
                + x1.x * (float)q8[4] + x1.y * (float)q8[5]
                + x1.z * (float)q8[6] + x1.w * (float)q8[7];
#pragma unroll
        for (int off = 32; off > 0; off >>= 1) p += __shfl_xor(p, off);
        if (l == 0) scrw[w][t] = p;
    }
    __syncthreads();
    if (tid < TRAJ)
        scr[tid] = scrw[0][tid] + scrw[1][tid] + scrw[2][tid] + scrw[3][tid];
    __syncthreads();

    const float inv = 0.04419417382415922f;  // 1/sqrt(512)
    float sv[TRAJ];
    float mx = -1e30f;
#pragma unroll
    for (int t = 0; t < TRAJ; ++t) { sv[t] = scr[t] * inv; mx = fmaxf(mx, sv[t]); }
    float ssum = 0.f;
#pragma unroll
    for (int t = 0; t < TRAJ; ++t) { sv[t] = expf(sv[t] - mx); ssum += sv[t]; }
    const float rs = 1.f / ssum;
#pragma unroll
    for (int t = 0; t < TRAJ; ++t) sv[t] *= rs;

    float o[8] = {0.f, 0.f, 0.f, 0.f, 0.f, 0.f, 0.f, 0.f};
#pragma unroll
    for (int t = 0; t < TRAJ; ++t) {
        f16x8 t8 = *(const f16x8*)(&tl[t][c0]);
#pragma unroll
        for (int i = 0; i < 8; ++i) o[i] += sv[t] * (float)t8[i];
    }
    f16x8 ho;
#pragma unroll
    for (int i = 0; i < 8; ++i) ho[i] = (_Float16)o[i];
    *(f16x8*)(wmixg + (size_t)n * TAU_ + c0) = ho;
}

// ---------- outgemm: out = wmixg @ Wv + bv  (batched, Wvt rows) ----------
__global__ __launch_bounds__(256) void outgemm(const _Float16* __restrict__ wmixg,
                                               const _Float16* __restrict__ Wvt,
                                               const float* __restrict__ bv,
                                               float* __restrict__ out)
{
    const int a0 = blockIdx.x * 8;   // grid 64
    const int tid = threadIdx.x;
    __shared__ _Float16 wl[8][TAU_];     // 32 KB
    __shared__ float pls[4][8][64];      // 8 KB

#pragma unroll
    for (int i = 0; i < 8; ++i) {
        const int slot = i * 256 + tid;
        const int row = slot >> 8;
        const int col = (slot & 255) * 8;
        *(f16x8*)(&wl[row][col]) = *(const f16x8*)(wmixg + (size_t)(a0 + row) * TAU_ + col);
    }
    __syncthreads();

    const int j = tid & 63;
    const int qh = tid >> 6;
    float pacc[8] = {0.f, 0.f, 0.f, 0.f, 0.f, 0.f, 0.f, 0.f};
    const _Float16* wv = Wvt + (size_t)j * TAU_ + qh * 512;
    for (int k = 0; k < 512; k += 8) {
        f16x8 w8 = *(const f16x8*)(wv + k);
        float wf[8];
#pragma unroll
        for (int i = 0; i < 8; ++i) wf[i] = (float)w8[i];
#pragma unroll
        for (int a = 0; a < 8; ++a) {
            f16x8 t8 = *(const f16x8*)(&wl[a][qh * 512 + k]);
#pragma unroll
            for (int i = 0; i < 8; ++i) pacc[a] += wf[i] * (float)t8[i];
        }
    }
#pragma unroll
    for (int a = 0; a < 8; ++a) pls[qh][a][j] = pacc[a];
    __syncthreads();

#pragma unroll
    for (int oo = 0; oo < 2; ++oo) {
        const int o = oo * 256 + tid;
        const int a = o >> 6, jj = o & 63;
        out[(size_t)(a0 + a) * DV_ + jj] =
            pls[0][a][jj] + pls[1][a][jj] + pls[2][a][jj] + pls[3][a][jj] + bv[jj];
    }
}

extern "C" void kernel_launch(void* const* d_in, const int* in_sizes, int n_in,
                              void* d_out, int out_size, void* d_ws, size_t ws_size,
                              hipStream_t stream)
{
    const float* traj = (const float*)d_in[0];  // [16,512,2048]
    const float* msgs = (const float*)d_in[1];  // [512, 32768]
    const float* Wq   = (const float*)d_in[2];  // [32768, 512]
    const float* bq   = (const float*)d_in[3];  // [512]
    const float* Wk   = (const float*)d_in[4];  // [2048, 512]
    const float* bk   = (const float*)d_in[5];  // [512] UNUSED (softmax-invariant)
    const float* Wv   = (const float*)d_in[6];  // [2048, 64]
    const float* bv   = (const float*)d_in[7];  // [64]
    float* out = (float*)d_out;                 // [512, 64]
    (void)bk;

    // ws: qpart f16 32MB | q f32 1MB. qk/Wvt/wmixg alias onto qpart (dead
    // after qreduce; all aliased writers run post-qreduce). Total 33 MB.
    _Float16* qpart = (_Float16*)d_ws;
    float*    q     = (float*)(qpart + (size_t)SPLITQ * N_AG * HID_);
    _Float16* qk    = qpart;                             // alias (2 MB)
    _Float16* Wvt   = qk + (size_t)N_AG * TAU_;          // alias (+0.25 MB)
    _Float16* wmixg = Wvt + (size_t)DV_ * TAU_;          // alias (+2 MB)

    qgemm<<<256, 512, 0, stream>>>(msgs, Wq, qpart);
    qreduce<<<128, 256, 0, stream>>>(qpart, bq, q);
    prep_wv<<<32, 256, 0, stream>>>(Wv, Wvt);
    qkgemm<<<256, 256, 0, stream>>>(q, Wk, qk);
    svmix<<<512, 256, 0, stream>>>(traj, qk, wmixg);
    outgemm<<<64, 256, 0, stream>>>(wmixg, Wvt, bv, out);
}

// Round 16
// 82.324 us; speedup vs baseline: 1.5210x; 1.3139x over previous
//
#include <hip/hip_runtime.h>
#include <hip/hip_fp16.h>

#define N_AG 512
#define TRAJ 16
#define TAU_ 2048
#define MSG_ 32768
#define HID_ 512
#define DV_ 64
#define SPLITQ 64
#define LDS_K 40            // qkgemm legacy layout

typedef _Float16 f16x8 __attribute__((ext_vector_type(8)));
typedef _Float16 f16x4 __attribute__((ext_vector_type(4)));
typedef _Float16 f16x2 __attribute__((ext_vector_type(2)));
typedef __fp16 h16x2 __attribute__((ext_vector_type(2)));
typedef float f32x4 __attribute__((ext_vector_type(4)));

// ---------- prep_wv: Wvt[j][k] = (f16) Wv[k][j]  (vectorized writes) -------
__global__ __launch_bounds__(256) void prep_wv(const float* __restrict__ Wv,
                                               _Float16* __restrict__ Wvt)
{
    __shared__ float td[64][65];
    const int k0 = blockIdx.x * 64;
    for (int e = threadIdx.x; e < 4096; e += 256) {
        const int ki = e >> 6, ni = e & 63;
        td[ki][ni] = Wv[(size_t)(k0 + ki) * DV_ + ni];
    }
    __syncthreads();
#pragma unroll
    for (int p = 0; p < 2; ++p) {
        const int u = p * 256 + threadIdx.x;
        const int ni = u >> 3, kj = (u & 7) * 8;
        f16x8 h;
#pragma unroll
        for (int i = 0; i < 8; ++i) h[i] = (_Float16)td[kj + i][ni];
        *(f16x8*)(Wvt + (size_t)ni * TAU_ + k0 + kj) = h;
    }
}

// ---------- qgemm: qpart[s] = msgs[:, sK] @ Wq[sK, :]  (256x256 tile) ------
// R11-proven loop (f32 staging, zero-conflict chunk-XOR LDS, depth-2,
// __syncthreads). NEW: LDS-staged epilogue -> dense 256B C-store runs
// (replaces scalar 2B stores whose 32B scattered runs cost ~4x write amp).
__global__ __launch_bounds__(512, 1) void qgemm(const float* __restrict__ X,
                                                const float* __restrict__ Wq,
                                                _Float16* __restrict__ qpart)
{
    // buf d: A @ d*32KB (16KB), B @ d*32KB+16KB (16KB)
    __shared__ __align__(1024) char smem[65536];
    const int tid = threadIdx.x;
    const int l = tid & 63;
    const int w = tid >> 6;
    const int wr = w >> 2, wc = w & 3;      // waves 2x4, wave tile 128x64
    const int r15 = l & 15;
    const int swz = ((l >> 4) ^ ((r15 >> 1) & 3)) * 16;

    const int b = blockIdx.x;
    const int sw = (b & 7) * 32 + (b >> 3);   // 256 = 8 XCD chunks of 32
    const int s = sw >> 2;                    // K-slice 0..63
    const int bm = (sw >> 1) & 1;
    const int bn = sw & 1;
    const size_t ks0 = (size_t)s * 512;

    // A staging: row am = tid>>1 (0..255), 16 floats at ak = (tid&1)*16
    const int am = tid >> 1;
    const int ak = (tid & 1) << 4;
    const float* agp = X + (size_t)(bm * 256 + am) * MSG_ + ks0 + ak;
    const int ac0 = ak >> 3;
    const int akey = (am >> 1) & 3;
    const int aoff0 = am * 64 + ((ac0 ^ akey)) * 16;
    const int aoff1 = am * 64 + (((ac0 + 1) ^ akey)) * 16;

    // B staging: col n = tid&255, 16 k's at kh0 = (tid>>8)*16 (k-strided)
    const int bn_ = tid & 255;
    const int kh0 = (tid >> 8) << 4;
    const float* bgp = Wq + (size_t)(ks0 + kh0) * HID_ + bn * 256 + bn_;
    const int bc0 = kh0 >> 3;
    const int bkey = (bn_ >> 1) & 3;
    const int boff0 = bn_ * 64 + ((bc0 ^ bkey)) * 16;
    const int boff1 = bn_ * 64 + (((bc0 + 1) ^ bkey)) * 16;

    f32x4 acc[8][4];
#pragma unroll
    for (int mi = 0; mi < 8; ++mi)
#pragma unroll
        for (int ni = 0; ni < 4; ++ni)
            acc[mi][ni] = (f32x4){0.f, 0.f, 0.f, 0.f};

    struct Stage { float4 a[4]; float bb[16]; };
    Stage rA, rB;
    const int nt = 16;                        // 512 / 32

    auto load_stage = [&](Stage& r, int t) {
        const float* ap = agp + t * 32;
#pragma unroll
        for (int i = 0; i < 4; ++i) r.a[i] = *(const float4*)(ap + 4 * i);
        const float* bp = bgp + (size_t)t * 32 * HID_;
#pragma unroll
        for (int i = 0; i < 16; ++i) r.bb[i] = bp[(size_t)i * HID_];
    };
    auto write_stage = [&](Stage& r, int d) {
        char* base = smem + d * 32768;
        const float* fa = (const float*)&r.a[0];
        union { h16x2 h2[4]; f16x8 v; } u0, u1;
        u0.h2[0] = __builtin_amdgcn_cvt_pkrtz(fa[0], fa[1]);
        u0.h2[1] = __builtin_amdgcn_cvt_pkrtz(fa[2], fa[3]);
        u0.h2[2] = __builtin_amdgcn_cvt_pkrtz(fa[4], fa[5]);
        u0.h2[3] = __builtin_amdgcn_cvt_pkrtz(fa[6], fa[7]);
        u1.h2[0] = __builtin_amdgcn_cvt_pkrtz(fa[8], fa[9]);
        u1.h2[1] = __builtin_amdgcn_cvt_pkrtz(fa[10], fa[11]);
        u1.h2[2] = __builtin_amdgcn_cvt_pkrtz(fa[12], fa[13]);
        u1.h2[3] = __builtin_amdgcn_cvt_pkrtz(fa[14], fa[15]);
        *(f16x8*)(base + aoff0) = u0.v;
        *(f16x8*)(base + aoff1) = u1.v;
        union { h16x2 h2[4]; f16x8 v; } v0, v1;
        v0.h2[0] = __builtin_amdgcn_cvt_pkrtz(r.bb[0], r.bb[1]);
        v0.h2[1] = __builtin_amdgcn_cvt_pkrtz(r.bb[2], r.bb[3]);
        v0.h2[2] = __builtin_amdgcn_cvt_pkrtz(r.bb[4], r.bb[5]);
        v0.h2[3] = __builtin_amdgcn_cvt_pkrtz(r.bb[6], r.bb[7]);
        v1.h2[0] = __builtin_amdgcn_cvt_pkrtz(r.bb[8], r.bb[9]);
        v1.h2[1] = __builtin_amdgcn_cvt_pkrtz(r.bb[10], r.bb[11]);
        v1.h2[2] = __builtin_amdgcn_cvt_pkrtz(r.bb[12], r.bb[13]);
        v1.h2[3] = __builtin_amdgcn_cvt_pkrtz(r.bb[14], r.bb[15]);
        *(f16x8*)(base + 16384 + boff0) = v0.v;
        *(f16x8*)(base + 16384 + boff1) = v1.v;
    };
    auto compute = [&](int d) {
        const char* ab = smem + d * 32768;
        const char* bb = smem + d * 32768 + 16384;
        f16x8 af[8], bf[4];
#pragma unroll
        for (int mi = 0; mi < 8; ++mi)
            af[mi] = *(const f16x8*)(ab + (wr * 128 + mi * 16 + r15) * 64 + swz);
#pragma unroll
        for (int ni = 0; ni < 4; ++ni)
            bf[ni] = *(const f16x8*)(bb + (wc * 64 + ni * 16 + r15) * 64 + swz);
#pragma unroll
        for (int mi = 0; mi < 8; ++mi)
#pragma unroll
            for (int ni = 0; ni < 4; ++ni)
                acc[mi][ni] = __builtin_amdgcn_mfma_f32_16x16x32_f16(
                    af[mi], bf[ni], acc[mi][ni], 0, 0, 0);
    };

    load_stage(rA, 0);
    load_stage(rB, 1);
    write_stage(rA, 0);
    __syncthreads();
    for (int t = 0; t < nt; t += 2) {
        if (t + 2 < nt) load_stage(rA, t + 2);
        compute(0);
        if (t + 1 < nt) write_stage(rB, 1);
        __syncthreads();
        if (t + 3 < nt) load_stage(rB, t + 3);
        compute(1);
        if (t + 2 < nt) write_stage(rA, 0);
        __syncthreads();
    }

    // ---- LDS-staged epilogue: 2 passes over column halves ----
    // acc element (mi,ni,r): row = wr*128+mi*16+(l>>4)*4+r (0..255),
    //                        col = wc*64+ni*16+r15          (0..255)
    // Pass H stages cols H*128..H*128+127 as [256][128] f16 (XOR-swizzled),
    // then all 512 threads store dense 256B/row runs.
    _Float16* cp = qpart + (size_t)s * (N_AG * HID_);
#pragma unroll
    for (int H = 0; H < 2; ++H) {
        __syncthreads();
        if ((wc >> 1) == H) {
#pragma unroll
            for (int mi = 0; mi < 8; ++mi)
#pragma unroll
                for (int ni = 0; ni < 4; ++ni) {
                    const int row = wr * 128 + mi * 16 + ((l >> 4) << 2);
                    const int colL = (wc & 1) * 64 + ni * 16 + r15;  // 0..127
#pragma unroll
                    for (int r = 0; r < 4; ++r) {
                        const int rr = row + r;
                        const int byte = rr * 256 + ((colL * 2) ^ ((rr & 7) << 4));
                        *(_Float16*)(smem + byte) = (_Float16)acc[mi][ni][r];
                    }
                }
        }
        __syncthreads();
#pragma unroll
        for (int it = 0; it < 8; ++it) {
            const int idx = it * 512 + tid;
            const int row = idx >> 4;          // 0..255
            const int c = idx & 15;            // 16B chunk
            const int byte = row * 256 + ((c * 16) ^ ((row & 7) << 4));
            f16x8 v = *(const f16x8*)(smem + byte);
            *(f16x8*)(cp + (size_t)(bm * 256 + row) * HID_
                      + bn * 256 + H * 128 + c * 8) = v;
        }
    }
}

// ---------- qreduce (vectorized): q = bq + sum_s qpart[s]  (f32) ----------
__global__ __launch_bounds__(256) void qreduce(const _Float16* __restrict__ qpart,
                                               const float* __restrict__ bq,
                                               float* __restrict__ q)
{
    const int e = (blockIdx.x * 256 + threadIdx.x) * 8;   // grid 128
    const int h0 = e & (HID_ - 1);
    float a[8];
#pragma unroll
    for (int i = 0; i < 8; ++i) a[i] = bq[h0 + i];
#pragma unroll
    for (int s = 0; s < SPLITQ; ++s) {
        f16x8 p = *(const f16x8*)(qpart + (size_t)s * (N_AG * HID_) + e);
#pragma unroll
        for (int i = 0; i < 8; ++i) a[i] += (float)p[i];
    }
    *(float4*)(q + e)     = (float4){a[0], a[1], a[2], a[3]};
    *(float4*)(q + e + 4) = (float4){a[4], a[5], a[6], a[7]};
}

// ---------- qkgemm: qk[n][c] = sum_h q[n,h]*Wk[c,h]  (64x64 tile) ----------
__global__ __launch_bounds__(256, 4) void qkgemm(const float* __restrict__ q,
                                                 const float* __restrict__ Wk,
                                                 _Float16* __restrict__ qk)
{
    __shared__ __align__(16) _Float16 smem[4 * 64 * LDS_K];
    _Float16* As = smem;
    _Float16* Bs = smem + 2 * 64 * LDS_K;
    const int tid = threadIdx.x;
    const int lane = tid & 63;
    const int wid = tid >> 6;
    const int wr = wid >> 1;
    const int wc = wid & 1;
    const int r15 = lane & 15;
    const int kblk = (lane >> 4) << 3;

    const int b = blockIdx.x;
    const int w = (b & 7) * 32 + (b >> 3);
    const int bm = w >> 5;
    const int bn = w & 31;

    const bool isB = tid >= 128;
    const int rt = tid & 127;
    const int srow = rt >> 1;
    const int skh = (rt & 1) << 4;
    const float* gp = (isB ? Wk + (size_t)(bn * 64) * HID_ : q + (size_t)(bm * 64) * HID_)
                      + (size_t)srow * HID_ + skh;
    _Float16* lbase = (isB ? Bs : As) + srow * LDS_K + skh;

    f32x4 acc[2][2];
#pragma unroll
    for (int mi = 0; mi < 2; ++mi)
#pragma unroll
        for (int ni = 0; ni < 2; ++ni)
            acc[mi][ni] = (f32x4){0.f, 0.f, 0.f, 0.f};

    float4 rA[4], rB[4];
    auto load_stage = [&](float4 (&r)[4], int ks) {
#pragma unroll
        for (int i = 0; i < 4; ++i) r[i] = *(const float4*)(gp + ks + 4 * i);
    };
    auto write_stage = [&](float4 (&r)[4], int buf) {
        const float* f = (const float*)&r[0];
        f16x8 h0, h1;
#pragma unroll
        for (int i = 0; i < 8; ++i) { h0[i] = (_Float16)f[i]; h1[i] = (_Float16)f[8 + i]; }
        *(f16x8*)(lbase + buf * 64 * LDS_K) = h0;
        *(f16x8*)(lbase + buf * 64 * LDS_K + 8) = h1;
    };
    auto compute = [&](int buf) {
        const _Float16* ab = As + buf * 64 * LDS_K;
        const _Float16* bbp = Bs + buf * 64 * LDS_K;
        f16x8 af[2], bf[2];
#pragma unroll
        for (int mi = 0; mi < 2; ++mi)
            af[mi] = *(const f16x8*)(ab + (wr * 32 + mi * 16 + r15) * LDS_K + kblk);
#pragma unroll
        for (int ni = 0; ni < 2; ++ni)
            bf[ni] = *(const f16x8*)(bbp + (wc * 32 + ni * 16 + r15) * LDS_K + kblk);
#pragma unroll
        for (int mi = 0; mi < 2; ++mi)
#pragma unroll
            for (int ni = 0; ni < 2; ++ni)
                acc[mi][ni] = __builtin_amdgcn_mfma_f32_16x16x32_f16(
                    af[mi], bf[ni], acc[mi][ni], 0, 0, 0);
    };

    load_stage(rA, 0);
    load_stage(rB, 32);
    write_stage(rA, 0);
    __syncthreads();
    for (int t = 0; t < 16; t += 2) {
        if (t + 2 < 16) load_stage(rA, (t + 2) << 5);
        compute(0);
        if (t + 1 < 16) write_stage(rB, 1);
        __syncthreads();
        if (t + 3 < 16) load_stage(rB, (t + 3) << 5);
        compute(1);
        if (t + 2 < 16) write_stage(rA, 0);
        __syncthreads();
    }
#pragma unroll
    for (int mi = 0; mi < 2; ++mi)
#pragma unroll
        for (int ni = 0; ni < 2; ++ni) {
            const int row = bm * 64 + wr * 32 + mi * 16 + ((lane >> 4) << 2);
            const int col = bn * 64 + wc * 32 + ni * 16 + r15;
#pragma unroll
            for (int r = 0; r < 4; ++r)
                qk[(size_t)(row + r) * TAU_ + col] = (_Float16)acc[mi][ni][r];
        }
}

// ---------- svmix: scores -> softmax -> mix -> out-projection (fused) ------
__global__ __launch_bounds__(256, 2) void svmix(const float* __restrict__ traj,
                                                const _Float16* __restrict__ qkm,
                                                const _Float16* __restrict__ Wvt,
                                                const float* __restrict__ bv,
                                                float* __restrict__ out)
{
    const int n = blockIdx.x;
    const int tid = threadIdx.x;
    const int w = tid >> 6;
    const int l = tid & 63;
    __shared__ _Float16 tl[TRAJ][TAU_];   // 64 KB
    __shared__ float scrw[4][TRAJ];
    __shared__ float scr[TRAJ];
    __shared__ _Float16 wmix[TAU_];       // 4 KB

    const int c0 = tid * 8;
    f16x8 q8 = *(const f16x8*)(qkm + (size_t)n * TAU_ + c0);

    // pass1: stream taus once -> LDS f16, partial dot vs qk
#pragma unroll
    for (int t = 0; t < TRAJ; ++t) {
        const float* tr = traj + ((size_t)(t * N_AG + n)) * TAU_ + c0;
        float4 x0 = *(const float4*)(tr);
        float4 x1 = *(const float4*)(tr + 4);
        union { h16x2 h2[4]; f16x8 v; } u;
        u.h2[0] = __builtin_amdgcn_cvt_pkrtz(x0.x, x0.y);
        u.h2[1] = __builtin_amdgcn_cvt_pkrtz(x0.z, x0.w);
        u.h2[2] = __builtin_amdgcn_cvt_pkrtz(x1.x, x1.y);
        u.h2[3] = __builtin_amdgcn_cvt_pkrtz(x1.z, x1.w);
        *(f16x8*)(&tl[t][c0]) = u.v;
        float p = x0.x * (float)q8[0] + x0.y * (float)q8[1]
                + x0.z * (float)q8[2] + x0.w * (float)q8[3]
                + x1.x * (float)q8[4] + x1.y * (float)q8[5]
                + x1.z * (float)q8[6] + x1.w * (float)q8[7];
#pragma unroll
        for (int off = 32; off > 0; off >>= 1) p += __shfl_xor(p, off);
        if (l == 0) scrw[w][t] = p;
    }
    __syncthreads();
    if (tid < TRAJ)
        scr[tid] = scrw[0][tid] + scrw[1][tid] + scrw[2][tid] + scrw[3][tid];
    __syncthreads();

    const float inv = 0.04419417382415922f;  // 1/sqrt(512)
    float sv[TRAJ];
    float mx = -1e30f;
#pragma unroll
    for (int t = 0; t < TRAJ; ++t) { sv[t] = scr[t] * inv; mx = fmaxf(mx, sv[t]); }
    float ssum = 0.f;
#pragma unroll
    for (int t = 0; t < TRAJ; ++t) { sv[t] = expf(sv[t] - mx); ssum += sv[t]; }
    const float rs = 1.f / ssum;
#pragma unroll
    for (int t = 0; t < TRAJ; ++t) sv[t] *= rs;

    // pass2: mix from LDS -> wmix (f16, LDS)
    float o[8] = {0.f, 0.f, 0.f, 0.f, 0.f, 0.f, 0.f, 0.f};
#pragma unroll
    for (int t = 0; t < TRAJ; ++t) {
        f16x8 t8 = *(const f16x8*)(&tl[t][c0]);
#pragma unroll
        for (int i = 0; i < 8; ++i) o[i] += sv[t] * (float)t8[i];
    }
    f16x8 ho;
#pragma unroll
    for (int i = 0; i < 8; ++i) ho[i] = (_Float16)o[i];
    *(f16x8*)(wmix + c0) = ho;
    __syncthreads();

    // pass3 (fused out-projection): wave w -> j = w*16+jj
#pragma unroll
    for (int jj = 0; jj < 16; ++jj) {
        const int j = w * 16 + jj;
        const _Float16* wvr = Wvt + (size_t)j * TAU_;
        float p = 0.f;
#pragma unroll
        for (int i = 0; i < 4; ++i) {
            const int off = i * 512 + l * 8;
            f16x8 a = *(const f16x8*)(wmix + off);
            f16x8 bb = *(const f16x8*)(wvr + off);
#pragma unroll
            for (int k = 0; k < 8; ++k) p += (float)a[k] * (float)bb[k];
        }
#pragma unroll
        for (int off = 32; off > 0; off >>= 1) p += __shfl_xor(p, off);
        if (l == 0) out[(size_t)n * DV_ + j] = p + bv[j];
    }
}

extern "C" void kernel_launch(void* const* d_in, const int* in_sizes, int n_in,
                              void* d_out, int out_size, void* d_ws, size_t ws_size,
                              hipStream_t stream)
{
    const float* traj = (const float*)d_in[0];  // [16,512,2048]
    const float* msgs = (const float*)d_in[1];  // [512, 32768]
    const float* Wq   = (const float*)d_in[2];  // [32768, 512]
    const float* bq   = (const float*)d_in[3];  // [512]
    const float* Wk   = (const float*)d_in[4];  // [2048, 512]
    const float* bk   = (const float*)d_in[5];  // [512] UNUSED (softmax-invariant)
    const float* Wv   = (const float*)d_in[6];  // [2048, 64]
    const float* bv   = (const float*)d_in[7];  // [64]
    float* out = (float*)d_out;                 // [512, 64]
    (void)bk;

    // ws: qpart f16 32MB | q f32 1MB. qk/Wvt alias onto qpart (dead after
    // qreduce; aliased writers run post-qreduce). Total 33 MB.
    _Float16* qpart = (_Float16*)d_ws;
    float*    q     = (float*)(qpart + (size_t)SPLITQ * N_AG * HID_);
    _Float16* qk    = qpart;                             // alias (2 MB)
    _Float16* Wvt   = qk + (size_t)N_AG * TAU_;          // alias (+0.25 MB)

    qgemm<<<256, 512, 0, stream>>>(msgs, Wq, qpart);
    qreduce<<<128, 256, 0, stream>>>(qpart, bq, q);
    prep_wv<<<32, 256, 0, stream>>>(Wv, Wvt);
    qkgemm<<<256, 256, 0, stream>>>(q, Wk, qk);
    svmix<<<512, 256, 0, stream>>>(traj, qk, Wvt, bv, out);
}